// Round 4
// baseline (854.536 us; speedup 1.0000x reference)
//
#include <hip/hip_runtime.h>
#include <cstdint>
#include <cstddef>

typedef unsigned short u16;
typedef unsigned int u32;
typedef __attribute__((ext_vector_type(8))) short bh8;
typedef __attribute__((ext_vector_type(4))) float fx4;

#define T_TOK 2048
#define D_DIM 1024
#define H_DIM 512
#define N_EXP 64
#define K_TOP 6
#define N_ASG (T_TOK * K_TOP)   // 12288

__device__ __forceinline__ float bf2f(u16 v) {
    union { u32 u; float f; } c; c.u = ((u32)v) << 16; return c.f;
}
__device__ __forceinline__ u16 f2bf(float f) {
    union { u32 u; float f; } c; c.f = f;
    u32 u = c.u;
    return (u16)((u + 0x7fffu + ((u >> 16) & 1u)) >> 16);
}

// ---------------- fused RMSNorm + router: writes xnb (bf16) AND raw (fp32) ----------------
__global__ __launch_bounds__(256) void routernorm_k(
    const float* __restrict__ x, const float* __restrict__ nw,
    const float* __restrict__ Wr, float* __restrict__ raw, u16* __restrict__ xnb)
{
    int t = blockIdx.x, tid = threadIdx.x;
    __shared__ float xs[D_DIM];
    __shared__ float ps[256];
    __shared__ float red[4];
    int d0 = tid << 2;
    float4 xv = *(const float4*)(x + (size_t)t * D_DIM + d0);
    float ss = xv.x * xv.x + xv.y * xv.y + xv.z * xv.z + xv.w * xv.w;
    #pragma unroll
    for (int o = 32; o > 0; o >>= 1) ss += __shfl_down(ss, o);
    if ((tid & 63) == 0) red[tid >> 6] = ss;
    __syncthreads();
    float ms = (red[0] + red[1] + red[2] + red[3]) * (1.f / (float)D_DIM);
    float sc = rsqrtf(ms + 1.1920929e-07f);
    float4 wv = *(const float4*)(nw + d0);
    float4 xf;
    xf.x = xv.x * sc * wv.x;
    xf.y = xv.y * sc * wv.y;
    xf.z = xv.z * sc * wv.z;
    xf.w = xv.w * sc * wv.w;
    *(float4*)&xs[d0] = xf;
    ushort4 ob;
    ob.x = f2bf(xf.x); ob.y = f2bf(xf.y); ob.z = f2bf(xf.z); ob.w = f2bf(xf.w);
    *(ushort4*)(xnb + (size_t)t * D_DIM + d0) = ob;
    __syncthreads();
    int e = tid & 63, part = tid >> 6;
    const float* wr = Wr + (size_t)e * D_DIM + part * 256;
    const float* xp = &xs[part * 256];
    float s = 0.f;
    #pragma unroll 8
    for (int i = 0; i < 256; i += 4) {
        float4 w4 = *(const float4*)(wr + i);
        s += xp[i] * w4.x + xp[i + 1] * w4.y + xp[i + 2] * w4.z + xp[i + 3] * w4.w;
    }
    ps[tid] = s;
    __syncthreads();
    if (part == 0) raw[(size_t)t * N_EXP + e] = ps[e] + ps[64 + e] + ps[128 + e] + ps[192 + e];
}

// ---------------- top-k (one wave per token), fp32 ----------------
__global__ void topk_k(const float* __restrict__ raw, const float* __restrict__ ebias,
                       int* __restrict__ cnt, int* __restrict__ tki, float* __restrict__ tkw)
{
    int t = blockIdx.x, lane = threadIdx.x;
    float r = raw[(size_t)t * N_EXP + lane];
    float cur = r + ebias[lane];
    int selI[K_TOP]; float selR[K_TOP];
    #pragma unroll
    for (int k = 0; k < K_TOP; ++k) {
        float v = cur; int id = lane;
        #pragma unroll
        for (int o = 32; o > 0; o >>= 1) {
            float v2 = __shfl_down(v, o); int i2 = __shfl_down(id, o);
            if (v2 > v || (v2 == v && i2 < id)) { v = v2; id = i2; }
        }
        id = __shfl(id, 0);
        if (lane == id) cur = -3.4e38f;
        selI[k] = id;
        selR[k] = __shfl(r, id);
    }
    float s = 0.f;
    #pragma unroll
    for (int k = 0; k < K_TOP; ++k) s += selR[k];
    if (lane < K_TOP) {
        tki[t * K_TOP + lane] = selI[lane];
        tkw[t * K_TOP + lane] = selR[lane] / s;
        atomicAdd(&cnt[selI[lane]], 1);
    }
}

__global__ void scan_k(const int* __restrict__ cnt, int* __restrict__ offs, int* __restrict__ fill)
{
    if (threadIdx.x == 0) {
        int s = 0;
        for (int e = 0; e < N_EXP; ++e) { offs[e] = s; fill[e] = s; s += cnt[e]; }
        offs[N_EXP] = s;
    }
}

__global__ void fill_k(const int* __restrict__ tki, const float* __restrict__ tkw,
                       int* __restrict__ fill, int* __restrict__ atok, float* __restrict__ aw)
{
    int t = blockIdx.x, lane = threadIdx.x;
    if (lane < K_TOP) {
        int e = tki[t * K_TOP + lane];
        int p = atomicAdd(&fill[e], 1);
        atok[p] = t;
        aw[p] = tkw[t * K_TOP + lane];
    }
}

// ---------------- weight convert to MFMA-fragment-packed bf16 ----------------
// in: fp32 [mat][K][N]. out per mat: frag(n_tile, kb) of 1KB:
//   offset_u16 = (n_tile*(K/32) + kb)*512 + lane*8;  elem j of lane l =
//   W[ kb*32 + (l>>4)*8 + j ][ n_tile*16 + (l&15) ]   (B-operand layout)
__global__ __launch_bounds__(256) void convF_k(
    const float* __restrict__ in, u16* __restrict__ out, int K, int N)
{
    int mat = blockIdx.z;
    size_t mo = (size_t)mat * K * N;
    int n0 = blockIdx.x << 6, k0 = blockIdx.y << 6;
    __shared__ u16 t[64][72];          // [n_local][k_local]
    int tid = threadIdx.x;
    int kr = tid >> 4, c4 = (tid & 15) << 2;
    #pragma unroll
    for (int rr = 0; rr < 4; ++rr) {
        int k = (rr << 4) + kr;
        float4 v = *(const float4*)(in + mo + (size_t)(k0 + k) * N + n0 + c4);
        t[c4 + 0][k] = f2bf(v.x);
        t[c4 + 1][k] = f2bf(v.y);
        t[c4 + 2][k] = f2bf(v.z);
        t[c4 + 3][k] = f2bf(v.w);
    }
    __syncthreads();
    int lane = tid & 63, g = tid >> 6;
    int nr = lane & 15, kq = lane >> 4;
    #pragma unroll
    for (int f = 0; f < 2; ++f) {
        int fragId = g + (f << 2);                 // (n_tile 0..3) x (kb 0..1)
        int ntile = fragId >> 1, kb = fragId & 1;
        bh8 v = *(const bh8*)&t[(ntile << 4) + nr][(kb << 5) + (kq << 3)];
        size_t fi = (((size_t)((n0 >> 4) + ntile) * (size_t)(K >> 5)
                      + (size_t)((k0 >> 5) + kb)) << 9) + (size_t)(lane << 3);
        *(bh8*)(out + mo + fi) = v;
    }
}

// ============ fused FFN v5: async LDS staging (global_load_lds) + 64-row slabs ============
// grid 8*9*32 1-D: xcd=id&7, rest=id>>3, grp=rest>>5, slab=rest&31.
//   grp<8: routed e=grp*8+xcd (all slabs of e on ONE xcd); grp==8: shared, f=slab*8+xcd<64.
// 64-row slab, 4 waves; wave w owns a 128-col panel, 4 row-tiles (acc 4x8 fx4 = 128 VGPR).
// B frags DMA'd to LDS double-buffer via global_load_lds (no VGPR round-trip, deep queue);
// one __syncthreads per K-step drains it. hG written in place over hA.
__global__ __launch_bounds__(256) void moe_ffn5_k(
    const u16* __restrict__ xnb,
    const u16* __restrict__ W1f,   // [66][frag-packed 512x1024]
    const u16* __restrict__ Wgf,   // [2][frag-packed 512x512] (0=routed,1=shared)
    const u16* __restrict__ W2f,   // [66][frag-packed 1024x512]
    const float* __restrict__ rb1, const float* __restrict__ rb2,
    const float* __restrict__ sb1, const float* __restrict__ sb2,
    const int* __restrict__ offs, const int* __restrict__ atok,
    const float* __restrict__ aw, float* __restrict__ accG)
{
    int id = blockIdx.x;
    int xcd = id & 7, rest = id >> 3, grp = rest >> 5, slab = rest & 31;
    int e, rowBase, end;
    bool routed;
    if (grp < 8) {
        e = (grp << 3) + xcd;
        routed = true;
        rowBase = offs[e] + (slab << 6);
        end = offs[e + 1];
    } else {
        int f = (slab << 3) + xcd;
        if (f >= 64) return;
        e = N_EXP + (f & 1);
        routed = false;
        rowBase = (f >> 1) << 6;
        end = T_TOK;
    }
    if (rowBase >= end) return;
    int rows = end - rowBase; if (rows > 64) rows = 64;

    __shared__ int   tok[64];
    __shared__ float wt[64];
    __shared__ u16 Bst[2 * 16384];   // 64KB: 2 x (4 waves x 8 frags x 1KB)
    __shared__ u16 hA[64 * 520];     // 66560B; becomes hG in place

    int tid = threadIdx.x;
    if (tid < 64) {
        int cl = rowBase + tid; if (cl >= end) cl = end - 1;
        tok[tid] = routed ? atok[cl] : cl;
        wt[tid]  = routed ? aw[cl] : 1.0f;
    }
    __syncthreads();

    int w = tid >> 6, lane = tid & 63, quad = lane >> 4, l15 = lane & 15;
    int n0w = w << 7;
    int laneOff = lane << 3;   // u16

    const u16* W1e = W1f + (size_t)e * (H_DIM * D_DIM);
    const u16* W2e = W2f + (size_t)e * (H_DIM * D_DIM);
    const u16* Wge = Wgf + (routed ? 0 : (size_t)(H_DIM * H_DIM));
    const float* b1 = routed ? rb1 + e * H_DIM : sb1 + (e - N_EXP) * H_DIM;
    const float* b2 = routed ? rb2 + e * D_DIM : sb2 + (e - N_EXP) * D_DIM;

    // async stage: 8 frags (8KB) for this wave into buffer cbuf
    auto stage8 = [&](const u16* src0, int ctStrideU16, int cbuf) {
        u16* d = Bst + (cbuf << 14) + (w << 12);
        const u16* s = src0 + laneOff;
        #pragma unroll
        for (int ct = 0; ct < 8; ++ct)
            __builtin_amdgcn_global_load_lds(
                (const __attribute__((address_space(1))) u32*)(s + ct * ctStrideU16),
                (__attribute__((address_space(3))) u32*)(d + (ct << 9)), 16, 0, 0);
    };

    // ---- phase 1: h = xn @ W1 + b1 (K=1024 -> N=512); A regs w/ 1-iter prefetch ----
    {
        const u16* ap0 = xnb + (size_t)tok[l15] * D_DIM + (quad << 3);
        const u16* ap1 = xnb + (size_t)tok[16 + l15] * D_DIM + (quad << 3);
        const u16* ap2 = xnb + (size_t)tok[32 + l15] * D_DIM + (quad << 3);
        const u16* ap3 = xnb + (size_t)tok[48 + l15] * D_DIM + (quad << 3);
        stage8(W1e + ((size_t)(w << 8) << 9), 16384, 0);
        bh8 aC0 = *(const bh8*)ap0, aC1 = *(const bh8*)ap1;
        bh8 aC2 = *(const bh8*)ap2, aC3 = *(const bh8*)ap3;
        fx4 ac[4][8] = {};
        __syncthreads();
        #pragma unroll 1
        for (int kbi = 0; kbi < 32; ++kbi) {
            int cur = kbi & 1;
            if (kbi < 31) stage8(W1e + ((size_t)((w << 8) + kbi + 1) << 9), 16384, cur ^ 1);
            bh8 aN0 = *(const bh8*)(ap0 + ((kbi + 1) << 5));   // kbi=31 overrun: workspace slack
            bh8 aN1 = *(const bh8*)(ap1 + ((kbi + 1) << 5));
            bh8 aN2 = *(const bh8*)(ap2 + ((kbi + 1) << 5));
            bh8 aN3 = *(const bh8*)(ap3 + ((kbi + 1) << 5));
            const u16* bb = Bst + (cur << 14) + (w << 12) + laneOff;
            #pragma unroll
            for (int ct = 0; ct < 8; ++ct) {
                bh8 b = *(const bh8*)(bb + (ct << 9));
                ac[0][ct] = __builtin_amdgcn_mfma_f32_16x16x32_bf16(aC0, b, ac[0][ct], 0, 0, 0);
                ac[1][ct] = __builtin_amdgcn_mfma_f32_16x16x32_bf16(aC1, b, ac[1][ct], 0, 0, 0);
                ac[2][ct] = __builtin_amdgcn_mfma_f32_16x16x32_bf16(aC2, b, ac[2][ct], 0, 0, 0);
                ac[3][ct] = __builtin_amdgcn_mfma_f32_16x16x32_bf16(aC3, b, ac[3][ct], 0, 0, 0);
            }
            aC0 = aN0; aC1 = aN1; aC2 = aN2; aC3 = aN3;
            __syncthreads();
        }
        #pragma unroll
        for (int ct = 0; ct < 8; ++ct) {
            int col = n0w + (ct << 4) + l15;
            float bv = b1[col];
            #pragma unroll
            for (int rt = 0; rt < 4; ++rt)
                #pragma unroll
                for (int r = 0; r < 4; ++r)
                    hA[((rt << 4) + (quad << 2) + r) * 520 + col] = f2bf(ac[rt][ct][r] + bv);
        }
    }

    // ---- phase 2: hg = h * silu(h @ Wg), in place over hA ----
    {
        stage8(Wge + ((size_t)(w << 7) << 9), 8192, 0);
        __syncthreads();   // hA writes visible + buf0 staged
        fx4 ac[4][8] = {};
        #pragma unroll 1
        for (int kbi = 0; kbi < 16; ++kbi) {
            int cur = kbi & 1;
            if (kbi < 15) stage8(Wge + ((size_t)((w << 7) + kbi + 1) << 9), 8192, cur ^ 1);
            const u16* hrow = hA + (kbi << 5) + (quad << 3);
            bh8 a0 = *(const bh8*)(hrow + (size_t)l15 * 520);
            bh8 a1 = *(const bh8*)(hrow + (size_t)(16 + l15) * 520);
            bh8 a2 = *(const bh8*)(hrow + (size_t)(32 + l15) * 520);
            bh8 a3 = *(const bh8*)(hrow + (size_t)(48 + l15) * 520);
            const u16* bb = Bst + (cur << 14) + (w << 12) + laneOff;
            #pragma unroll
            for (int ct = 0; ct < 8; ++ct) {
                bh8 b = *(const bh8*)(bb + (ct << 9));
                ac[0][ct] = __builtin_amdgcn_mfma_f32_16x16x32_bf16(a0, b, ac[0][ct], 0, 0, 0);
                ac[1][ct] = __builtin_amdgcn_mfma_f32_16x16x32_bf16(a1, b, ac[1][ct], 0, 0, 0);
                ac[2][ct] = __builtin_amdgcn_mfma_f32_16x16x32_bf16(a2, b, ac[2][ct], 0, 0, 0);
                ac[3][ct] = __builtin_amdgcn_mfma_f32_16x16x32_bf16(a3, b, ac[3][ct], 0, 0, 0);
            }
            __syncthreads();
        }
        #pragma unroll
        for (int ct = 0; ct < 8; ++ct) {
            int col = n0w + (ct << 4) + l15;
            #pragma unroll
            for (int rt = 0; rt < 4; ++rt)
                #pragma unroll
                for (int r = 0; r < 4; ++r) {
                    int row = (rt << 4) + (quad << 2) + r;
                    float g = ac[rt][ct][r];
                    float h = bf2f(hA[row * 520 + col]);
                    hA[row * 520 + col] = f2bf(h * g * (1.f / (1.f + __expf(-g))));
                }
        }
    }

    // ---- phase 3: acc[tok] += wt * (hg @ W2 + b2) (K=512 -> N=1024, 2 halves/wave) ----
    stage8(W2e + ((size_t)(w << 8) << 9), 8192, 0);
    __syncthreads();   // hG writes visible + buf0 staged
    #pragma unroll 1
    for (int half = 0; half < 2; ++half) {
        fx4 ac[4][8] = {};
        #pragma unroll 1
        for (int kk = 0; kk < 16; ++kk) {
            int gIt = (half << 4) + kk, cur = gIt & 1, nIt = gIt + 1;
            if (nIt < 32)
                stage8(W2e + ((size_t)((w << 8) + ((nIt >> 4) << 7) + (nIt & 15)) << 9), 8192, cur ^ 1);
            const u16* hrow = hA + (kk << 5) + (quad << 3);
            bh8 a0 = *(const bh8*)(hrow + (size_t)l15 * 520);
            bh8 a1 = *(const bh8*)(hrow + (size_t)(16 + l15) * 520);
            bh8 a2 = *(const bh8*)(hrow + (size_t)(32 + l15) * 520);
            bh8 a3 = *(const bh8*)(hrow + (size_t)(48 + l15) * 520);
            const u16* bb = Bst + (cur << 14) + (w << 12) + laneOff;
            #pragma unroll
            for (int ct = 0; ct < 8; ++ct) {
                bh8 b = *(const bh8*)(bb + (ct << 9));
                ac[0][ct] = __builtin_amdgcn_mfma_f32_16x16x32_bf16(a0, b, ac[0][ct], 0, 0, 0);
                ac[1][ct] = __builtin_amdgcn_mfma_f32_16x16x32_bf16(a1, b, ac[1][ct], 0, 0, 0);
                ac[2][ct] = __builtin_amdgcn_mfma_f32_16x16x32_bf16(a2, b, ac[2][ct], 0, 0, 0);
                ac[3][ct] = __builtin_amdgcn_mfma_f32_16x16x32_bf16(a3, b, ac[3][ct], 0, 0, 0);
            }
            __syncthreads();
        }
        int n0 = (w << 8) + (half << 7);
        #pragma unroll
        for (int ct = 0; ct < 8; ++ct) {
            int col = n0 + (ct << 4) + l15;
            float bv = b2[col];
            #pragma unroll
            for (int rt = 0; rt < 4; ++rt)
                #pragma unroll
                for (int r = 0; r < 4; ++r) {
                    int row = (rt << 4) + (quad << 2) + r;
                    if (row < rows)
                        atomicAdd(&accG[(size_t)tok[row] * D_DIM + col],
                                  wt[row] * (ac[rt][ct][r] + bv));
                }
        }
    }
}

// ============ fallback fused FFN (raw fp32 weights), used only if workspace too small ============
template<int ROUTED>
__global__ __launch_bounds__(256) void moe_ffn_k(
    const u16* __restrict__ xnb,
    const float* __restrict__ W1b, const float* __restrict__ Wg,
    const float* __restrict__ W2b,
    const float* __restrict__ b1b, const float* __restrict__ b2b,
    const int* __restrict__ offs, const int* __restrict__ atok,
    const float* __restrict__ aw, float* __restrict__ accG)
{
    int e = blockIdx.z;
    int start = ROUTED ? offs[e] : 0;
    int end   = ROUTED ? offs[e + 1] : T_TOK;
    int rowBase = start + (blockIdx.y << 5);
    if (rowBase >= end) return;
    int rows = end - rowBase; if (rows > 32) rows = 32;

    __shared__ int   tok[32];
    __shared__ float wt[32];
    __shared__ u16 hA[32 * 520];
    __shared__ u16 hG[32 * 520];
    __shared__ u16 As[32 * 32];
    __shared__ u16 Bs[64 * 36];

    int tid = threadIdx.x;
    if (tid < 32) {
        int cl = rowBase + tid; if (cl >= end) cl = end - 1;
        tok[tid] = ROUTED ? atok[cl] : cl;
        wt[tid]  = ROUTED ? aw[cl] : 1.0f;
    }
    __syncthreads();

    const float* W1 = W1b + (size_t)e * (D_DIM * H_DIM);
    const float* W2 = W2b + (size_t)e * (D_DIM * H_DIM);
    const float* b1 = b1b + e * H_DIM;
    const float* b2 = b2b + e * D_DIM;

    int w = tid >> 6, lane = tid & 63, quad = lane >> 4, l15 = lane & 15;
    int sr2 = tid >> 3, sc2 = (tid & 7) << 2;

    for (int nc = 0; nc < 8; ++nc) {
        int n0 = nc << 6;
        fx4 a0 = {}; fx4 a1 = {};
        for (int kc = 0; kc < 32; ++kc) {
            int kb = kc << 5;
            int2 av = *(const int2*)(xnb + (size_t)tok[sr2] * D_DIM + kb + sc2);
            const float* cp = W1 + n0 + lane;
            int kx = kb + (w << 3);
            u32 p[4];
            #pragma unroll
            for (int jj = 0; jj < 4; ++jj) {
                u32 lo = f2bf(cp[(size_t)(kx + 2 * jj) * H_DIM]);
                u32 hi = f2bf(cp[(size_t)(kx + 2 * jj + 1) * H_DIM]);
                p[jj] = lo | (hi << 16);
            }
            __syncthreads();
            *(int2*)&As[sr2 * 32 + sc2] = av;
            u16* bsw = &Bs[lane * 36 + (w << 3)];
            uint2 q0; q0.x = p[0]; q0.y = p[1];
            uint2 q1; q1.x = p[2]; q1.y = p[3];
            *(uint2*)bsw = q0;
            *(uint2*)(bsw + 4) = q1;
            __syncthreads();
            bh8 af0 = *(const bh8*)&As[l15 * 32 + (quad << 3)];
            bh8 af1 = *(const bh8*)&As[(16 + l15) * 32 + (quad << 3)];
            const u16* brp = &Bs[((w << 4) + l15) * 36 + (quad << 3)];
            union { bh8 v; uint2 u2[2]; } bf;
            bf.u2[0] = *(const uint2*)brp;
            bf.u2[1] = *(const uint2*)(brp + 4);
            a0 = __builtin_amdgcn_mfma_f32_16x16x32_bf16(af0, bf.v, a0, 0, 0, 0);
            a1 = __builtin_amdgcn_mfma_f32_16x16x32_bf16(af1, bf.v, a1, 0, 0, 0);
        }
        int col = n0 + (w << 4) + l15;
        float bv = b1[col];
        #pragma unroll
        for (int r = 0; r < 4; ++r) {
            hA[((quad << 2) + r) * 520 + col]      = f2bf(a0[r] + bv);
            hA[(16 + (quad << 2) + r) * 520 + col] = f2bf(a1[r] + bv);
        }
    }
    __syncthreads();

    for (int nc = 0; nc < 8; ++nc) {
        int n0 = nc << 6;
        fx4 a0 = {}; fx4 a1 = {};
        for (int kc = 0; kc < 16; ++kc) {
            int kb = kc << 5;
            const float* cp = Wg + n0 + lane;
            int kx = kb + (w << 3);
            u32 p[4];
            #pragma unroll
            for (int jj = 0; jj < 4; ++jj) {
                u32 lo = f2bf(cp[(size_t)(kx + 2 * jj) * H_DIM]);
                u32 hi = f2bf(cp[(size_t)(kx + 2 * jj + 1) * H_DIM]);
                p[jj] = lo | (hi << 16);
            }
            __syncthreads();
            u16* bsw = &Bs[lane * 36 + (w << 3)];
            uint2 q0; q0.x = p[0]; q0.y = p[1];
            uint2 q1; q1.x = p[2]; q1.y = p[3];
            *(uint2*)bsw = q0;
            *(uint2*)(bsw + 4) = q1;
            __syncthreads();
            bh8 af0 = *(const bh8*)&hA[l15 * 520 + kb + (quad << 3)];
            bh8 af1 = *(const bh8*)&hA[(16 + l15) * 520 + kb + (quad << 3)];
            const u16* brp = &Bs[((w << 4) + l15) * 36 + (quad << 3)];
            union { bh8 v; uint2 u2[2]; } bf;
            bf.u2[0] = *(const uint2*)brp;
            bf.u2[1] = *(const uint2*)(brp + 4);
            a0 = __builtin_amdgcn_mfma_f32_16x16x32_bf16(af0, bf.v, a0, 0, 0, 0);
            a1 = __builtin_amdgcn_mfma_f32_16x16x32_bf16(af1, bf.v, a1, 0, 0, 0);
        }
        int col = n0 + (w << 4) + l15;
        #pragma unroll
        for (int r = 0; r < 4; ++r) {
            int r0 = (quad << 2) + r;
            float h0 = bf2f(hA[r0 * 520 + col]);
            float g0 = a0[r];
            hG[r0 * 520 + col] = f2bf(h0 * g0 * (1.f / (1.f + __expf(-g0))));
            int r1 = 16 + r0;
            float h1 = bf2f(hA[r1 * 520 + col]);
            float g1 = a1[r];
            hG[r1 * 520 + col] = f2bf(h1 * g1 * (1.f / (1.f + __expf(-g1))));
        }
    }
    __syncthreads();

    for (int nc = 0; nc < 16; ++nc) {
        int n0 = nc << 6;
        fx4 a0 = {}; fx4 a1 = {};
        for (int kc = 0; kc < 16; ++kc) {
            int kb = kc << 5;
            const float* cp = W2 + n0 + lane;
            int kx = kb + (w << 3);
            u32 p[4];
            #pragma unroll
            for (int jj = 0; jj < 4; ++jj) {
                u32 lo = f2bf(cp[(size_t)(kx + 2 * jj) * D_DIM]);
                u32 hi = f2bf(cp[(size_t)(kx + 2 * jj + 1) * D_DIM]);
                p[jj] = lo | (hi << 16);
            }
            __syncthreads();
            u16* bsw = &Bs[lane * 36 + (w << 3)];
            uint2 q0; q0.x = p[0]; q0.y = p[1];
            uint2 q1; q1.x = p[2]; q1.y = p[3];
            *(uint2*)bsw = q0;
            *(uint2*)(bsw + 4) = q1;
            __syncthreads();
            bh8 af0 = *(const bh8*)&hG[l15 * 520 + kb + (quad << 3)];
            bh8 af1 = *(const bh8*)&hG[(16 + l15) * 520 + kb + (quad << 3)];
            const u16* brp = &Bs[((w << 4) + l15) * 36 + (quad << 3)];
            union { bh8 v; uint2 u2[2]; } bf;
            bf.u2[0] = *(const uint2*)brp;
            bf.u2[1] = *(const uint2*)(brp + 4);
            a0 = __builtin_amdgcn_mfma_f32_16x16x32_bf16(af0, bf.v, a0, 0, 0, 0);
            a1 = __builtin_amdgcn_mfma_f32_16x16x32_bf16(af1, bf.v, a1, 0, 0, 0);
        }
        int col = n0 + (w << 4) + l15;
        float bv = b2[col];
        #pragma unroll
        for (int r = 0; r < 4; ++r) {
            int lr0 = (quad << 2) + r;
            if (lr0 < rows)
                atomicAdd(&accG[(size_t)tok[lr0] * D_DIM + col], wt[lr0] * (a0[r] + bv));
            int lr1 = 16 + lr0;
            if (lr1 < rows)
                atomicAdd(&accG[(size_t)tok[lr1] * D_DIM + col], wt[lr1] * (a1[r] + bv));
        }
    }
}

// ---------------- final: out = x + acc (all fp32) ----------------
__global__ __launch_bounds__(256) void final_k(
    const float* __restrict__ x, const float* __restrict__ acc, float* __restrict__ out)
{
    size_t i = ((size_t)blockIdx.x * 256 + threadIdx.x) << 2;
    float4 xv = *(const float4*)(x + i);
    float4 a = *(const float4*)(acc + i);
    float4 o;
    o.x = xv.x + a.x;
    o.y = xv.y + a.y;
    o.z = xv.z + a.z;
    o.w = xv.w + a.w;
    *(float4*)(out + i) = o;
}

extern "C" void kernel_launch(void* const* d_in, const int* in_sizes, int n_in,
                              void* d_out, int out_size, void* d_ws, size_t ws_size,
                              hipStream_t stream)
{
    const float* x     = (const float*)d_in[0];
    const float* nw    = (const float*)d_in[1];
    const float* Wr    = (const float*)d_in[2];
    const float* sW1   = (const float*)d_in[3];
    const float* sb1   = (const float*)d_in[4];
    const float* sW2   = (const float*)d_in[5];
    const float* sb2   = (const float*)d_in[6];
    const float* sWg   = (const float*)d_in[7];
    const float* rW1   = (const float*)d_in[8];
    const float* rb1   = (const float*)d_in[9];
    const float* rW2   = (const float*)d_in[10];
    const float* rb2   = (const float*)d_in[11];
    const float* rWg   = (const float*)d_in[12];
    const float* ebias = (const float*)d_in[13];
    float* out = (float*)d_out;
    (void)in_sizes; (void)n_in; (void)out_size;

    char* wp = (char*)d_ws;
    auto alloc = [&](size_t b) { char* p = wp; wp += (b + 255) & ~(size_t)255; return p; };
    int*   cnt  = (int*)alloc(N_EXP * 4);
    int*   offs = (int*)alloc((N_EXP + 1) * 4);
    int*   fill = (int*)alloc(N_EXP * 4);
    int*   tki  = (int*)alloc((size_t)T_TOK * K_TOP * 4);
    float* tkw  = (float*)alloc((size_t)T_TOK * K_TOP * 4);
    int*   atok = (int*)alloc((size_t)N_ASG * 4);
    float* aw   = (float*)alloc((size_t)N_ASG * 4);
    float* raw  = (float*)alloc((size_t)T_TOK * N_EXP * 4);
    u16*   xnb  = (u16*)alloc((size_t)T_TOK * D_DIM * 2);
    float* acc  = (float*)alloc((size_t)T_TOK * D_DIM * 4);
    // fast-path: fragment-packed bf16 weights, 66 experts (64 routed + 2 shared)
    u16* W1f = (u16*)alloc((size_t)(N_EXP + 2) * H_DIM * D_DIM * 2);
    u16* W2f = (u16*)alloc((size_t)(N_EXP + 2) * H_DIM * D_DIM * 2);
    u16* Wgf = (u16*)alloc((size_t)2 * H_DIM * H_DIM * 2);
    alloc(1 << 16);   // slack pad: A-prefetch overruns land here, never used
    bool fast = (size_t)(wp - (char*)d_ws) <= ws_size;

    hipMemsetAsync(cnt, 0, N_EXP * 4, stream);
    hipMemsetAsync(acc, 0, (size_t)T_TOK * D_DIM * 4, stream);

    dim3 b256(256);
    routernorm_k<<<T_TOK, b256, 0, stream>>>(x, nw, Wr, raw, xnb);
    topk_k<<<T_TOK, dim3(64), 0, stream>>>(raw, ebias, cnt, tki, tkw);
    scan_k<<<1, dim3(64), 0, stream>>>(cnt, offs, fill);
    fill_k<<<T_TOK, dim3(64), 0, stream>>>(tki, tkw, fill, atok, aw);

    if (fast) {
        size_t ms = (size_t)H_DIM * D_DIM;
        convF_k<<<dim3(H_DIM / 64, D_DIM / 64, N_EXP), b256, 0, stream>>>(rW1, W1f, D_DIM, H_DIM);
        convF_k<<<dim3(H_DIM / 64, D_DIM / 64, 2), b256, 0, stream>>>(sW1, W1f + (size_t)N_EXP * ms, D_DIM, H_DIM);
        convF_k<<<dim3(D_DIM / 64, H_DIM / 64, N_EXP), b256, 0, stream>>>(rW2, W2f, H_DIM, D_DIM);
        convF_k<<<dim3(D_DIM / 64, H_DIM / 64, 2), b256, 0, stream>>>(sW2, W2f + (size_t)N_EXP * ms, H_DIM, D_DIM);
        convF_k<<<dim3(H_DIM / 64, H_DIM / 64, 1), b256, 0, stream>>>(rWg, Wgf, H_DIM, H_DIM);
        convF_k<<<dim3(H_DIM / 64, H_DIM / 64, 1), b256, 0, stream>>>(sWg, Wgf + (size_t)H_DIM * H_DIM, H_DIM, H_DIM);

        moe_ffn5_k<<<dim3(8 * 9 * 32), b256, 0, stream>>>(
            xnb, W1f, Wgf, W2f, rb1, rb2, sb1, sb2, offs, atok, aw, acc);
    } else {
        moe_ffn_k<1><<<dim3(1, 64, N_EXP), b256, 0, stream>>>(
            xnb, rW1, rWg, rW2, rb1, rb2, offs, atok, aw, acc);
        moe_ffn_k<0><<<dim3(1, 64, 2), b256, 0, stream>>>(
            xnb, sW1, sWg, sW2, sb1, sb2, offs, atok, aw, acc);
    }

    final_k<<<(T_TOK * D_DIM) / 1024, b256, 0, stream>>>(x, acc, out);
}

// Round 5
// 716.555 us; speedup vs baseline: 1.1926x; 1.1926x over previous
//
#include <hip/hip_runtime.h>
#include <cstdint>
#include <cstddef>

typedef unsigned short u16;
typedef unsigned int u32;
typedef __attribute__((ext_vector_type(8))) short bh8;
typedef __attribute__((ext_vector_type(4))) float fx4;

#define T_TOK 2048
#define D_DIM 1024
#define H_DIM 512
#define N_EXP 64
#define K_TOP 6
#define N_ASG (T_TOK * K_TOP)   // 12288

__device__ __forceinline__ float bf2f(u16 v) {
    union { u32 u; float f; } c; c.u = ((u32)v) << 16; return c.f;
}
__device__ __forceinline__ u16 f2bf(float f) {
    union { u32 u; float f; } c; c.f = f;
    u32 u = c.u;
    return (u16)((u + 0x7fffu + ((u >> 16) & 1u)) >> 16);
}

// ---------------- fused RMSNorm + router: writes xnb (bf16) AND raw (fp32) ----------------
__global__ __launch_bounds__(256) void routernorm_k(
    const float* __restrict__ x, const float* __restrict__ nw,
    const float* __restrict__ Wr, float* __restrict__ raw, u16* __restrict__ xnb)
{
    int t = blockIdx.x, tid = threadIdx.x;
    __shared__ float xs[D_DIM];
    __shared__ float ps[256];
    __shared__ float red[4];
    int d0 = tid << 2;
    float4 xv = *(const float4*)(x + (size_t)t * D_DIM + d0);
    float ss = xv.x * xv.x + xv.y * xv.y + xv.z * xv.z + xv.w * xv.w;
    #pragma unroll
    for (int o = 32; o > 0; o >>= 1) ss += __shfl_down(ss, o);
    if ((tid & 63) == 0) red[tid >> 6] = ss;
    __syncthreads();
    float ms = (red[0] + red[1] + red[2] + red[3]) * (1.f / (float)D_DIM);
    float sc = rsqrtf(ms + 1.1920929e-07f);
    float4 wv = *(const float4*)(nw + d0);
    float4 xf;
    xf.x = xv.x * sc * wv.x;
    xf.y = xv.y * sc * wv.y;
    xf.z = xv.z * sc * wv.z;
    xf.w = xv.w * sc * wv.w;
    *(float4*)&xs[d0] = xf;
    ushort4 ob;
    ob.x = f2bf(xf.x); ob.y = f2bf(xf.y); ob.z = f2bf(xf.z); ob.w = f2bf(xf.w);
    *(ushort4*)(xnb + (size_t)t * D_DIM + d0) = ob;
    __syncthreads();
    int e = tid & 63, part = tid >> 6;
    const float* wr = Wr + (size_t)e * D_DIM + part * 256;
    const float* xp = &xs[part * 256];
    float s = 0.f;
    #pragma unroll 8
    for (int i = 0; i < 256; i += 4) {
        float4 w4 = *(const float4*)(wr + i);
        s += xp[i] * w4.x + xp[i + 1] * w4.y + xp[i + 2] * w4.z + xp[i + 3] * w4.w;
    }
    ps[tid] = s;
    __syncthreads();
    if (part == 0) raw[(size_t)t * N_EXP + e] = ps[e] + ps[64 + e] + ps[128 + e] + ps[192 + e];
}

// ---------------- top-k (one wave per token), fp32 ----------------
__global__ void topk_k(const float* __restrict__ raw, const float* __restrict__ ebias,
                       int* __restrict__ cnt, int* __restrict__ tki, float* __restrict__ tkw)
{
    int t = blockIdx.x, lane = threadIdx.x;
    float r = raw[(size_t)t * N_EXP + lane];
    float cur = r + ebias[lane];
    int selI[K_TOP]; float selR[K_TOP];
    #pragma unroll
    for (int k = 0; k < K_TOP; ++k) {
        float v = cur; int id = lane;
        #pragma unroll
        for (int o = 32; o > 0; o >>= 1) {
            float v2 = __shfl_down(v, o); int i2 = __shfl_down(id, o);
            if (v2 > v || (v2 == v && i2 < id)) { v = v2; id = i2; }
        }
        id = __shfl(id, 0);
        if (lane == id) cur = -3.4e38f;
        selI[k] = id;
        selR[k] = __shfl(r, id);
    }
    float s = 0.f;
    #pragma unroll
    for (int k = 0; k < K_TOP; ++k) s += selR[k];
    if (lane < K_TOP) {
        tki[t * K_TOP + lane] = selI[lane];
        tkw[t * K_TOP + lane] = selR[lane] / s;
        atomicAdd(&cnt[selI[lane]], 1);
    }
}

// parallel 64-lane exclusive scan (replaces serial single-thread loop)
__global__ void scan_k(const int* __restrict__ cnt, int* __restrict__ offs, int* __restrict__ fill)
{
    int lane = threadIdx.x;          // 64
    int c = cnt[lane];
    int s = c;
    #pragma unroll
    for (int o = 1; o < 64; o <<= 1) {
        int v = __shfl_up(s, o);
        if (lane >= o) s += v;
    }
    int excl = s - c;
    offs[lane] = excl;
    fill[lane] = excl;
    if (lane == 63) offs[N_EXP] = s;
}

__global__ void fill_k(const int* __restrict__ tki, const float* __restrict__ tkw,
                       int* __restrict__ fill, int* __restrict__ atok, float* __restrict__ aw)
{
    int t = blockIdx.x, lane = threadIdx.x;
    if (lane < K_TOP) {
        int e = tki[t * K_TOP + lane];
        int p = atomicAdd(&fill[e], 1);
        atok[p] = t;
        aw[p] = tkw[t * K_TOP + lane];
    }
}

// ---------------- merged weight convert to MFMA-fragment-packed bf16 (ONE launch) ----------------
// Jobs: [0, 66*128)           -> W1 mats (K=1024, N=512), 128 tiles each (8 x 16)
//       [66*128, 2*66*128)    -> W2 mats (K=512,  N=1024), 128 tiles each (16 x 8)
//       [2*66*128, +2*64)     -> Wg mats (K=512,  N=512),   64 tiles each (8 x 8)
// frag layout per mat: offset_u16 = (n_tile*(K/32) + kb)*512 + lane*8; elem j of lane l =
//   W[kb*32 + (l>>4)*8 + j][n_tile*16 + (l&15)]   (B-operand layout)
__global__ __launch_bounds__(256) void convAll_k(
    const float* __restrict__ rW1, const float* __restrict__ sW1,
    const float* __restrict__ rW2, const float* __restrict__ sW2,
    const float* __restrict__ rWg, const float* __restrict__ sWg,
    u16* __restrict__ W1f, u16* __restrict__ W2f, u16* __restrict__ Wgf)
{
    int id = blockIdx.x;
    const float* src; u16* dst;
    int K, N, n0, k0;
    const size_t MS = (size_t)H_DIM * D_DIM;     // 524288
    if (id < 66 * 128) {
        int mat = id >> 7, tile = id & 127;
        K = D_DIM; N = H_DIM;
        src = (mat < N_EXP ? rW1 + (size_t)mat * MS : sW1 + (size_t)(mat - N_EXP) * MS);
        dst = W1f + (size_t)mat * MS;
        n0 = (tile & 7) << 6; k0 = (tile >> 3) << 6;
    } else if (id < 2 * 66 * 128) {
        id -= 66 * 128;
        int mat = id >> 7, tile = id & 127;
        K = H_DIM; N = D_DIM;
        src = (mat < N_EXP ? rW2 + (size_t)mat * MS : sW2 + (size_t)(mat - N_EXP) * MS);
        dst = W2f + (size_t)mat * MS;
        n0 = (tile & 15) << 6; k0 = (tile >> 4) << 6;
    } else {
        id -= 2 * 66 * 128;
        int mat = id >> 6, tile = id & 63;
        K = H_DIM; N = H_DIM;
        src = (mat == 0 ? rWg : sWg);
        dst = Wgf + (size_t)mat * (H_DIM * H_DIM);
        n0 = (tile & 7) << 6; k0 = (tile >> 3) << 6;
    }

    __shared__ u16 t[64][72];          // [n_local][k_local]
    int tid = threadIdx.x;
    int kr = tid >> 4, c4 = (tid & 15) << 2;
    #pragma unroll
    for (int rr = 0; rr < 4; ++rr) {
        int k = (rr << 4) + kr;
        float4 v = *(const float4*)(src + (size_t)(k0 + k) * N + n0 + c4);
        t[c4 + 0][k] = f2bf(v.x);
        t[c4 + 1][k] = f2bf(v.y);
        t[c4 + 2][k] = f2bf(v.z);
        t[c4 + 3][k] = f2bf(v.w);
    }
    __syncthreads();
    int lane = tid & 63, g = tid >> 6;
    int nr = lane & 15, kq = lane >> 4;
    #pragma unroll
    for (int f = 0; f < 2; ++f) {
        int fragId = g + (f << 2);                 // (n_tile 0..3) x (kb 0..1)
        int ntile = fragId >> 1, kb = fragId & 1;
        bh8 v = *(const bh8*)&t[(ntile << 4) + nr][(kb << 5) + (kq << 3)];
        size_t fi = (((size_t)((n0 >> 4) + ntile) * (size_t)(K >> 5)
                      + (size_t)((k0 >> 5) + kb)) << 9) + (size_t)(lane << 3);
        *(bh8*)(dst + fi) = v;
    }
}

// ============ fused FFN v6: XCD-affine + reg double-buffer, VGPR budget 256 ============
// Identical structure to v4 (barrier-free K-loops, frag-packed B direct from global),
// but __launch_bounds__(256, 2): min 2 waves/EU -> VGPR cap 256, so the explicit
// register double buffer (acc 64 + bA/bB 64 + A 16) survives regalloc instead of
// collapsing to load->wait->MFMA (v4 was capped at 112 VGPR; v3/v4 identical perf).
__global__ __launch_bounds__(256, 2) void moe_ffn6_k(
    const u16* __restrict__ xnb,
    const u16* __restrict__ W1f,   // [66][frag-packed 512x1024]
    const u16* __restrict__ Wgf,   // [2][frag-packed 512x512] (0=routed,1=shared)
    const u16* __restrict__ W2f,   // [66][frag-packed 1024x512]
    const float* __restrict__ rb1, const float* __restrict__ rb2,
    const float* __restrict__ sb1, const float* __restrict__ sb2,
    const int* __restrict__ offs, const int* __restrict__ atok,
    const float* __restrict__ aw, float* __restrict__ accG)
{
    int id = blockIdx.x;
    int xcd = id & 7, rest = id >> 3, grp = rest >> 6, slab = rest & 63;
    int e, rowBase, end;
    bool routed;
    if (grp < 8) {
        e = (grp << 3) + xcd;
        routed = true;
        rowBase = offs[e] + (slab << 5);
        end = offs[e + 1];
    } else {
        int f = (slab << 3) + xcd;
        if (f >= 128) return;
        e = N_EXP + (f & 1);
        routed = false;
        rowBase = (f >> 1) << 5;
        end = T_TOK;
    }
    if (rowBase >= end) return;
    int rows = end - rowBase; if (rows > 32) rows = 32;

    __shared__ int   tok[32];
    __shared__ float wt[32];
    __shared__ u16 hA[32 * 520];   // 33280B; rewritten in place as hG after phase 2

    int tid = threadIdx.x;
    if (tid < 32) {
        int cl = rowBase + tid; if (cl >= end) cl = end - 1;
        tok[tid] = routed ? atok[cl] : cl;
        wt[tid]  = routed ? aw[cl] : 1.0f;
    }
    __syncthreads();

    int w = tid >> 6, lane = tid & 63, quad = lane >> 4, l15 = lane & 15;
    int n0w = w << 7;

    const u16* W1e = W1f + (size_t)e * (H_DIM * D_DIM);
    const u16* W2e = W2f + (size_t)e * (H_DIM * D_DIM);
    const u16* Wge = Wgf + (routed ? 0 : (size_t)(H_DIM * H_DIM));
    const float* b1 = routed ? rb1 + e * H_DIM : sb1 + (e - N_EXP) * H_DIM;
    const float* b2 = routed ? rb2 + e * D_DIM : sb2 + (e - N_EXP) * D_DIM;

    // ---- phase 1: h = xn @ W1 + b1 (K=1024 -> N=512); A direct from global ----
    {
        const u16* a0p = xnb + (size_t)tok[l15] * D_DIM + (quad << 3);
        const u16* a1p = xnb + (size_t)tok[16 + l15] * D_DIM + (quad << 3);
        const u16* bp  = W1e + ((size_t)w << 17) + (lane << 3);
        fx4 ac0[8] = {}, ac1[8] = {};
        bh8 bA[8], bB[8], aA0, aA1, aB0, aB1;
        #pragma unroll
        for (int ct = 0; ct < 8; ++ct) bA[ct] = *(const bh8*)(bp + (ct << 14));
        aA0 = *(const bh8*)a0p;
        aA1 = *(const bh8*)a1p;
        #pragma unroll 1
        for (int kbi = 0; kbi < 32; kbi += 2) {
            #pragma unroll
            for (int ct = 0; ct < 8; ++ct) bB[ct] = *(const bh8*)(bp + (((ct << 5) + kbi + 1) << 9));
            aB0 = *(const bh8*)(a0p + ((kbi + 1) << 5));
            aB1 = *(const bh8*)(a1p + ((kbi + 1) << 5));
            #pragma unroll
            for (int ct = 0; ct < 8; ++ct) {
                ac0[ct] = __builtin_amdgcn_mfma_f32_16x16x32_bf16(aA0, bA[ct], ac0[ct], 0, 0, 0);
                ac1[ct] = __builtin_amdgcn_mfma_f32_16x16x32_bf16(aA1, bA[ct], ac1[ct], 0, 0, 0);
            }
            #pragma unroll
            for (int ct = 0; ct < 8; ++ct) bA[ct] = *(const bh8*)(bp + (((ct << 5) + kbi + 2) << 9));
            aA0 = *(const bh8*)(a0p + ((kbi + 2) << 5));   // last prefetch: slack-safe garbage
            aA1 = *(const bh8*)(a1p + ((kbi + 2) << 5));
            #pragma unroll
            for (int ct = 0; ct < 8; ++ct) {
                ac0[ct] = __builtin_amdgcn_mfma_f32_16x16x32_bf16(aB0, bB[ct], ac0[ct], 0, 0, 0);
                ac1[ct] = __builtin_amdgcn_mfma_f32_16x16x32_bf16(aB1, bB[ct], ac1[ct], 0, 0, 0);
            }
        }
        #pragma unroll
        for (int ct = 0; ct < 8; ++ct) {
            int col = n0w + (ct << 4) + l15;
            float bv = b1[col];
            #pragma unroll
            for (int r = 0; r < 4; ++r) {
                int r0 = (quad << 2) + r;
                hA[r0 * 520 + col]        = f2bf(ac0[ct][r] + bv);
                hA[(16 + r0) * 520 + col] = f2bf(ac1[ct][r] + bv);
            }
        }
    }
    __syncthreads();

    // ---- phase 2: hg = h * silu(h @ Wg), in place over hA ----
    {
        const u16* A0 = hA + l15 * 520 + (quad << 3);
        const u16* A1 = hA + (16 + l15) * 520 + (quad << 3);
        const u16* bp = Wge + ((size_t)w << 16) + (lane << 3);
        fx4 ac0[8] = {}, ac1[8] = {};
        bh8 bA[8], bB[8], aA0, aA1, aB0, aB1;
        #pragma unroll
        for (int ct = 0; ct < 8; ++ct) bA[ct] = *(const bh8*)(bp + (ct << 13));
        aA0 = *(const bh8*)A0;
        aA1 = *(const bh8*)A1;
        #pragma unroll 1
        for (int kbi = 0; kbi < 16; kbi += 2) {
            #pragma unroll
            for (int ct = 0; ct < 8; ++ct) bB[ct] = *(const bh8*)(bp + (((ct << 4) + kbi + 1) << 9));
            aB0 = *(const bh8*)(A0 + ((kbi + 1) << 5));
            aB1 = *(const bh8*)(A1 + ((kbi + 1) << 5));
            #pragma unroll
            for (int ct = 0; ct < 8; ++ct) {
                ac0[ct] = __builtin_amdgcn_mfma_f32_16x16x32_bf16(aA0, bA[ct], ac0[ct], 0, 0, 0);
                ac1[ct] = __builtin_amdgcn_mfma_f32_16x16x32_bf16(aA1, bA[ct], ac1[ct], 0, 0, 0);
            }
            #pragma unroll
            for (int ct = 0; ct < 8; ++ct) bA[ct] = *(const bh8*)(bp + (((ct << 4) + kbi + 2) << 9));
            aA0 = *(const bh8*)(A0 + ((kbi + 2) << 5));
            aA1 = *(const bh8*)(A1 + ((kbi + 2) << 5));
            #pragma unroll
            for (int ct = 0; ct < 8; ++ct) {
                ac0[ct] = __builtin_amdgcn_mfma_f32_16x16x32_bf16(aB0, bB[ct], ac0[ct], 0, 0, 0);
                ac1[ct] = __builtin_amdgcn_mfma_f32_16x16x32_bf16(aB1, bB[ct], ac1[ct], 0, 0, 0);
            }
        }
        __syncthreads();   // all hA fragment reads complete before in-place rewrite
        #pragma unroll
        for (int ct = 0; ct < 8; ++ct) {
            int col = n0w + (ct << 4) + l15;
            #pragma unroll
            for (int r = 0; r < 4; ++r) {
                int r0 = (quad << 2) + r;
                float g0 = ac0[ct][r];
                float h0 = bf2f(hA[r0 * 520 + col]);
                hA[r0 * 520 + col] = f2bf(h0 * g0 * (1.f / (1.f + __expf(-g0))));
                int r1 = 16 + r0;
                float g1 = ac1[ct][r];
                float h1 = bf2f(hA[r1 * 520 + col]);
                hA[r1 * 520 + col] = f2bf(h1 * g1 * (1.f / (1.f + __expf(-g1))));
            }
        }
    }
    __syncthreads();

    // ---- phase 3: acc[tok] += wt * (hg @ W2 + b2) (K=512 -> N=1024, 2 halves/wave) ----
    #pragma unroll 1
    for (int half = 0; half < 2; ++half) {
        int n0 = (w << 8) + (half << 7);
        const u16* A0 = hA + l15 * 520 + (quad << 3);
        const u16* A1 = hA + (16 + l15) * 520 + (quad << 3);
        const u16* bp = W2e + (((size_t)((w << 4) + (half << 3))) << 13) + (lane << 3);
        fx4 ac0[8] = {}, ac1[8] = {};
        bh8 bA[8], bB[8], aA0, aA1, aB0, aB1;
        #pragma unroll
        for (int ct = 0; ct < 8; ++ct) bA[ct] = *(const bh8*)(bp + (ct << 13));
        aA0 = *(const bh8*)A0;
        aA1 = *(const bh8*)A1;
        #pragma unroll 1
        for (int kbi = 0; kbi < 16; kbi += 2) {
            #pragma unroll
            for (int ct = 0; ct < 8; ++ct) bB[ct] = *(const bh8*)(bp + (((ct << 4) + kbi + 1) << 9));
            aB0 = *(const bh8*)(A0 + ((kbi + 1) << 5));
            aB1 = *(const bh8*)(A1 + ((kbi + 1) << 5));
            #pragma unroll
            for (int ct = 0; ct < 8; ++ct) {
                ac0[ct] = __builtin_amdgcn_mfma_f32_16x16x32_bf16(aA0, bA[ct], ac0[ct], 0, 0, 0);
                ac1[ct] = __builtin_amdgcn_mfma_f32_16x16x32_bf16(aA1, bA[ct], ac1[ct], 0, 0, 0);
            }
            #pragma unroll
            for (int ct = 0; ct < 8; ++ct) bA[ct] = *(const bh8*)(bp + (((ct << 4) + kbi + 2) << 9));
            aA0 = *(const bh8*)(A0 + ((kbi + 2) << 5));
            aA1 = *(const bh8*)(A1 + ((kbi + 2) << 5));
            #pragma unroll
            for (int ct = 0; ct < 8; ++ct) {
                ac0[ct] = __builtin_amdgcn_mfma_f32_16x16x32_bf16(aB0, bB[ct], ac0[ct], 0, 0, 0);
                ac1[ct] = __builtin_amdgcn_mfma_f32_16x16x32_bf16(aB1, bB[ct], ac1[ct], 0, 0, 0);
            }
        }
        #pragma unroll
        for (int ct = 0; ct < 8; ++ct) {
            int col = n0 + (ct << 4) + l15;
            float bv = b2[col];
            #pragma unroll
            for (int r = 0; r < 4; ++r) {
                int r0 = (quad << 2) + r;
                if (r0 < rows)
                    atomicAdd(&accG[(size_t)tok[r0] * D_DIM + col], wt[r0] * (ac0[ct][r] + bv));
                int r1 = 16 + r0;
                if (r1 < rows)
                    atomicAdd(&accG[(size_t)tok[r1] * D_DIM + col], wt[r1] * (ac1[ct][r] + bv));
            }
        }
    }
}

// ============ fallback fused FFN (raw fp32 weights), used only if workspace too small ============
template<int ROUTED>
__global__ __launch_bounds__(256) void moe_ffn_k(
    const u16* __restrict__ xnb,
    const float* __restrict__ W1b, const float* __restrict__ Wg,
    const float* __restrict__ W2b,
    const float* __restrict__ b1b, const float* __restrict__ b2b,
    const int* __restrict__ offs, const int* __restrict__ atok,
    const float* __restrict__ aw, float* __restrict__ accG)
{
    int e = blockIdx.z;
    int start = ROUTED ? offs[e] : 0;
    int end   = ROUTED ? offs[e + 1] : T_TOK;
    int rowBase = start + (blockIdx.y << 5);
    if (rowBase >= end) return;
    int rows = end - rowBase; if (rows > 32) rows = 32;

    __shared__ int   tok[32];
    __shared__ float wt[32];
    __shared__ u16 hA[32 * 520];
    __shared__ u16 hG[32 * 520];
    __shared__ u16 As[32 * 32];
    __shared__ u16 Bs[64 * 36];

    int tid = threadIdx.x;
    if (tid < 32) {
        int cl = rowBase + tid; if (cl >= end) cl = end - 1;
        tok[tid] = ROUTED ? atok[cl] : cl;
        wt[tid]  = ROUTED ? aw[cl] : 1.0f;
    }
    __syncthreads();

    const float* W1 = W1b + (size_t)e * (D_DIM * H_DIM);
    const float* W2 = W2b + (size_t)e * (D_DIM * H_DIM);
    const float* b1 = b1b + e * H_DIM;
    const float* b2 = b2b + e * D_DIM;

    int w = tid >> 6, lane = tid & 63, quad = lane >> 4, l15 = lane & 15;
    int sr2 = tid >> 3, sc2 = (tid & 7) << 2;

    for (int nc = 0; nc < 8; ++nc) {
        int n0 = nc << 6;
        fx4 a0 = {}; fx4 a1 = {};
        for (int kc = 0; kc < 32; ++kc) {
            int kb = kc << 5;
            int2 av = *(const int2*)(xnb + (size_t)tok[sr2] * D_DIM + kb + sc2);
            const float* cp = W1 + n0 + lane;
            int kx = kb + (w << 3);
            u32 p[4];
            #pragma unroll
            for (int jj = 0; jj < 4; ++jj) {
                u32 lo = f2bf(cp[(size_t)(kx + 2 * jj) * H_DIM]);
                u32 hi = f2bf(cp[(size_t)(kx + 2 * jj + 1) * H_DIM]);
                p[jj] = lo | (hi << 16);
            }
            __syncthreads();
            *(int2*)&As[sr2 * 32 + sc2] = av;
            u16* bsw = &Bs[lane * 36 + (w << 3)];
            uint2 q0; q0.x = p[0]; q0.y = p[1];
            uint2 q1; q1.x = p[2]; q1.y = p[3];
            *(uint2*)bsw = q0;
            *(uint2*)(bsw + 4) = q1;
            __syncthreads();
            bh8 af0 = *(const bh8*)&As[l15 * 32 + (quad << 3)];
            bh8 af1 = *(const bh8*)&As[(16 + l15) * 32 + (quad << 3)];
            const u16* brp = &Bs[((w << 4) + l15) * 36 + (quad << 3)];
            union { bh8 v; uint2 u2[2]; } bf;
            bf.u2[0] = *(const uint2*)brp;
            bf.u2[1] = *(const uint2*)(brp + 4);
            a0 = __builtin_amdgcn_mfma_f32_16x16x32_bf16(af0, bf.v, a0, 0, 0, 0);
            a1 = __builtin_amdgcn_mfma_f32_16x16x32_bf16(af1, bf.v, a1, 0, 0, 0);
        }
        int col = n0 + (w << 4) + l15;
        float bv = b1[col];
        #pragma unroll
        for (int r = 0; r < 4; ++r) {
            hA[((quad << 2) + r) * 520 + col]      = f2bf(a0[r] + bv);
            hA[(16 + (quad << 2) + r) * 520 + col] = f2bf(a1[r] + bv);
        }
    }
    __syncthreads();

    for (int nc = 0; nc < 8; ++nc) {
        int n0 = nc << 6;
        fx4 a0 = {}; fx4 a1 = {};
        for (int kc = 0; kc < 16; ++kc) {
            int kb = kc << 5;
            const float* cp = Wg + n0 + lane;
            int kx = kb + (w << 3);
            u32 p[4];
            #pragma unroll
            for (int jj = 0; jj < 4; ++jj) {
                u32 lo = f2bf(cp[(size_t)(kx + 2 * jj) * H_DIM]);
                u32 hi = f2bf(cp[(size_t)(kx + 2 * jj + 1) * H_DIM]);
                p[jj] = lo | (hi << 16);
            }
            __syncthreads();
            u16* bsw = &Bs[lane * 36 + (w << 3)];
            uint2 q0; q0.x = p[0]; q0.y = p[1];
            uint2 q1; q1.x = p[2]; q1.y = p[3];
            *(uint2*)bsw = q0;
            *(uint2*)(bsw + 4) = q1;
            __syncthreads();
            bh8 af0 = *(const bh8*)&hA[l15 * 520 + kb + (quad << 3)];
            bh8 af1 = *(const bh8*)&hA[(16 + l15) * 520 + kb + (quad << 3)];
            const u16* brp = &Bs[((w << 4) + l15) * 36 + (quad << 3)];
            union { bh8 v; uint2 u2[2]; } bf;
            bf.u2[0] = *(const uint2*)brp;
            bf.u2[1] = *(const uint2*)(brp + 4);
            a0 = __builtin_amdgcn_mfma_f32_16x16x32_bf16(af0, bf.v, a0, 0, 0, 0);
            a1 = __builtin_amdgcn_mfma_f32_16x16x32_bf16(af1, bf.v, a1, 0, 0, 0);
        }
        int col = n0 + (w << 4) + l15;
        #pragma unroll
        for (int r = 0; r < 4; ++r) {
            int r0 = (quad << 2) + r;
            float h0 = bf2f(hA[r0 * 520 + col]);
            float g0 = a0[r];
            hG[r0 * 520 + col] = f2bf(h0 * g0 * (1.f / (1.f + __expf(-g0))));
            int r1 = 16 + r0;
            float h1 = bf2f(hA[r1 * 520 + col]);
            float g1 = a1[r];
            hG[r1 * 520 + col] = f2bf(h1 * g1 * (1.f / (1.f + __expf(-g1))));
        }
    }
    __syncthreads();

    for (int nc = 0; nc < 16; ++nc) {
        int n0 = nc << 6;
        fx4 a0 = {}; fx4 a1 = {};
        for (int kc = 0; kc < 16; ++kc) {
            int kb = kc << 5;
            const float* cp = W2 + n0 + lane;
            int kx = kb + (w << 3);
            u32 p[4];
            #pragma unroll
            for (int jj = 0; jj < 4; ++jj) {
                u32 lo = f2bf(cp[(size_t)(kx + 2 * jj) * D_DIM]);
                u32 hi = f2bf(cp[(size_t)(kx + 2 * jj + 1) * D_DIM]);
                p[jj] = lo | (hi << 16);
            }
            __syncthreads();
            u16* bsw = &Bs[lane * 36 + (w << 3)];
            uint2 q0; q0.x = p[0]; q0.y = p[1];
            uint2 q1; q1.x = p[2]; q1.y = p[3];
            *(uint2*)bsw = q0;
            *(uint2*)(bsw + 4) = q1;
            __syncthreads();
            bh8 af0 = *(const bh8*)&hG[l15 * 520 + kb + (quad << 3)];
            bh8 af1 = *(const bh8*)&hG[(16 + l15) * 520 + kb + (quad << 3)];
            const u16* brp = &Bs[((w << 4) + l15) * 36 + (quad << 3)];
            union { bh8 v; uint2 u2[2]; } bf;
            bf.u2[0] = *(const uint2*)brp;
            bf.u2[1] = *(const uint2*)(brp + 4);
            a0 = __builtin_amdgcn_mfma_f32_16x16x32_bf16(af0, bf.v, a0, 0, 0, 0);
            a1 = __builtin_amdgcn_mfma_f32_16x16x32_bf16(af1, bf.v, a1, 0, 0, 0);
        }
        int col = n0 + (w << 4) + l15;
        float bv = b2[col];
        #pragma unroll
        for (int r = 0; r < 4; ++r) {
            int lr0 = (quad << 2) + r;
            if (lr0 < rows)
                atomicAdd(&accG[(size_t)tok[lr0] * D_DIM + col], wt[lr0] * (a0[r] + bv));
            int lr1 = 16 + lr0;
            if (lr1 < rows)
                atomicAdd(&accG[(size_t)tok[lr1] * D_DIM + col], wt[lr1] * (a1[r] + bv));
        }
    }
}

// ---------------- final: out = x + acc (all fp32) ----------------
__global__ __launch_bounds__(256) void final_k(
    const float* __restrict__ x, const float* __restrict__ acc, float* __restrict__ out)
{
    size_t i = ((size_t)blockIdx.x * 256 + threadIdx.x) << 2;
    float4 xv = *(const float4*)(x + i);
    float4 a = *(const float4*)(acc + i);
    float4 o;
    o.x = xv.x + a.x;
    o.y = xv.y + a.y;
    o.z = xv.z + a.z;
    o.w = xv.w + a.w;
    *(float4*)(out + i) = o;
}

extern "C" void kernel_launch(void* const* d_in, const int* in_sizes, int n_in,
                              void* d_out, int out_size, void* d_ws, size_t ws_size,
                              hipStream_t stream)
{
    const float* x     = (const float*)d_in[0];
    const float* nw    = (const float*)d_in[1];
    const float* Wr    = (const float*)d_in[2];
    const float* sW1   = (const float*)d_in[3];
    const float* sb1   = (const float*)d_in[4];
    const float* sW2   = (const float*)d_in[5];
    const float* sb2   = (const float*)d_in[6];
    const float* sWg   = (const float*)d_in[7];
    const float* rW1   = (const float*)d_in[8];
    const float* rb1   = (const float*)d_in[9];
    const float* rW2   = (const float*)d_in[10];
    const float* rb2   = (const float*)d_in[11];
    const float* rWg   = (const float*)d_in[12];
    const float* ebias = (const float*)d_in[13];
    float* out = (float*)d_out;
    (void)in_sizes; (void)n_in; (void)out_size;

    char* wp = (char*)d_ws;
    auto alloc = [&](size_t b) { char* p = wp; wp += (b + 255) & ~(size_t)255; return p; };
    int*   cnt  = (int*)alloc(N_EXP * 4);
    int*   offs = (int*)alloc((N_EXP + 1) * 4);
    int*   fill = (int*)alloc(N_EXP * 4);
    int*   tki  = (int*)alloc((size_t)T_TOK * K_TOP * 4);
    float* tkw  = (float*)alloc((size_t)T_TOK * K_TOP * 4);
    int*   atok = (int*)alloc((size_t)N_ASG * 4);
    float* aw   = (float*)alloc((size_t)N_ASG * 4);
    float* raw  = (float*)alloc((size_t)T_TOK * N_EXP * 4);
    u16*   xnb  = (u16*)alloc((size_t)T_TOK * D_DIM * 2);
    float* acc  = (float*)alloc((size_t)T_TOK * D_DIM * 4);
    // fast-path: fragment-packed bf16 weights, 66 experts (64 routed + 2 shared)
    u16* W1f = (u16*)alloc((size_t)(N_EXP + 2) * H_DIM * D_DIM * 2);
    u16* W2f = (u16*)alloc((size_t)(N_EXP + 2) * H_DIM * D_DIM * 2);
    u16* Wgf = (u16*)alloc((size_t)2 * H_DIM * H_DIM * 2);
    alloc(1 << 16);   // slack pad: A-prefetch overruns land here, never used
    bool fast = (size_t)(wp - (char*)d_ws) <= ws_size;

    hipMemsetAsync(cnt, 0, N_EXP * 4, stream);
    hipMemsetAsync(acc, 0, (size_t)T_TOK * D_DIM * 4, stream);

    dim3 b256(256);
    routernorm_k<<<T_TOK, b256, 0, stream>>>(x, nw, Wr, raw, xnb);
    topk_k<<<T_TOK, dim3(64), 0, stream>>>(raw, ebias, cnt, tki, tkw);
    scan_k<<<1, dim3(64), 0, stream>>>(cnt, offs, fill);
    fill_k<<<T_TOK, dim3(64), 0, stream>>>(tki, tkw, fill, atok, aw);

    if (fast) {
        convAll_k<<<dim3(2 * 66 * 128 + 2 * 64), b256, 0, stream>>>(
            rW1, sW1, rW2, sW2, rWg, sWg, W1f, W2f, Wgf);

        moe_ffn6_k<<<dim3(8 * 9 * 64), b256, 0, stream>>>(
            xnb, W1f, Wgf, W2f, rb1, rb2, sb1, sb2, offs, atok, aw, acc);
    } else {
        moe_ffn_k<1><<<dim3(1, 64, N_EXP), b256, 0, stream>>>(
            xnb, rW1, rWg, rW2, rb1, rb2, offs, atok, aw, acc);
        moe_ffn_k<0><<<dim3(1, 64, 2), b256, 0, stream>>>(
            xnb, sW1, sWg, sW2, sb1, sb2, offs, atok, aw, acc);
    }

    final_k<<<(T_TOK * D_DIM) / 1024, b256, 0, stream>>>(x, acc, out);
}

// Round 6
// 651.650 us; speedup vs baseline: 1.3113x; 1.0996x over previous
//
#include <hip/hip_runtime.h>
#include <cstdint>
#include <cstddef>

typedef unsigned short u16;
typedef unsigned int u32;
typedef __attribute__((ext_vector_type(8))) short bh8;
typedef __attribute__((ext_vector_type(4))) float fx4;

#define T_TOK 2048
#define D_DIM 1024
#define H_DIM 512
#define N_EXP 64
#define K_TOP 6
#define N_ASG (T_TOK * K_TOP)   // 12288
#define R_TOT (N_ASG + 2 * T_TOK)   // 16384 rows in h-space
#define GRID_E (8 * 9 * 64)         // 4608

__device__ __forceinline__ float bf2f(u16 v) {
    union { u32 u; float f; } c; c.u = ((u32)v) << 16; return c.f;
}
__device__ __forceinline__ u16 f2bf(float f) {
    union { u32 u; float f; } c; c.f = f;
    u32 u = c.u;
    return (u16)((u + 0x7fffu + ((u >> 16) & 1u)) >> 16);
}

// ---------------- fused RMSNorm + router, 4 tokens/block (Wr reuse x4) ----------------
__global__ __launch_bounds__(256) void rn4_k(
    const float* __restrict__ x, const float* __restrict__ nw,
    const float* __restrict__ Wr, float* __restrict__ raw, u16* __restrict__ xnb)
{
    int t0 = blockIdx.x << 2, tid = threadIdx.x;
    __shared__ float xs[4][D_DIM];      // 16KB
    __shared__ float ps[4][256];        // 4KB
    __shared__ float red4[4][4];
    int d0 = tid << 2;
    float4 wv = *(const float4*)(nw + d0);
    float4 xv[4];
    #pragma unroll
    for (int tt = 0; tt < 4; ++tt) {
        xv[tt] = *(const float4*)(x + (size_t)(t0 + tt) * D_DIM + d0);
        float ss = xv[tt].x * xv[tt].x + xv[tt].y * xv[tt].y
                 + xv[tt].z * xv[tt].z + xv[tt].w * xv[tt].w;
        #pragma unroll
        for (int o = 32; o > 0; o >>= 1) ss += __shfl_down(ss, o);
        if ((tid & 63) == 0) red4[tt][tid >> 6] = ss;
    }
    __syncthreads();
    #pragma unroll
    for (int tt = 0; tt < 4; ++tt) {
        float ms = (red4[tt][0] + red4[tt][1] + red4[tt][2] + red4[tt][3]) * (1.f / (float)D_DIM);
        float sc = rsqrtf(ms + 1.1920929e-07f);
        float4 xf;
        xf.x = xv[tt].x * sc * wv.x;
        xf.y = xv[tt].y * sc * wv.y;
        xf.z = xv[tt].z * sc * wv.z;
        xf.w = xv[tt].w * sc * wv.w;
        *(float4*)&xs[tt][d0] = xf;
        ushort4 ob;
        ob.x = f2bf(xf.x); ob.y = f2bf(xf.y); ob.z = f2bf(xf.z); ob.w = f2bf(xf.w);
        *(ushort4*)(xnb + (size_t)(t0 + tt) * D_DIM + d0) = ob;
    }
    __syncthreads();
    int e = tid & 63, part = tid >> 6;
    const float* wr = Wr + (size_t)e * D_DIM + part * 256;
    float s0 = 0.f, s1 = 0.f, s2 = 0.f, s3 = 0.f;
    const float* xp0 = &xs[0][part * 256];
    const float* xp1 = &xs[1][part * 256];
    const float* xp2 = &xs[2][part * 256];
    const float* xp3 = &xs[3][part * 256];
    #pragma unroll 4
    for (int i = 0; i < 256; i += 4) {
        float4 w4 = *(const float4*)(wr + i);
        s0 += xp0[i] * w4.x + xp0[i+1] * w4.y + xp0[i+2] * w4.z + xp0[i+3] * w4.w;
        s1 += xp1[i] * w4.x + xp1[i+1] * w4.y + xp1[i+2] * w4.z + xp1[i+3] * w4.w;
        s2 += xp2[i] * w4.x + xp2[i+1] * w4.y + xp2[i+2] * w4.z + xp2[i+3] * w4.w;
        s3 += xp3[i] * w4.x + xp3[i+1] * w4.y + xp3[i+2] * w4.z + xp3[i+3] * w4.w;
    }
    ps[0][tid] = s0; ps[1][tid] = s1; ps[2][tid] = s2; ps[3][tid] = s3;
    __syncthreads();
    if (part == 0) {
        #pragma unroll
        for (int tt = 0; tt < 4; ++tt)
            raw[(size_t)(t0 + tt) * N_EXP + e] =
                ps[tt][e] + ps[tt][64 + e] + ps[tt][128 + e] + ps[tt][192 + e];
    }
}

// ---------------- top-k (one wave per token), fp32 ----------------
__global__ void topk_k(const float* __restrict__ raw, const float* __restrict__ ebias,
                       int* __restrict__ cnt, int* __restrict__ tki, float* __restrict__ tkw)
{
    int t = blockIdx.x, lane = threadIdx.x;
    float r = raw[(size_t)t * N_EXP + lane];
    float cur = r + ebias[lane];
    int selI[K_TOP]; float selR[K_TOP];
    #pragma unroll
    for (int k = 0; k < K_TOP; ++k) {
        float v = cur; int id = lane;
        #pragma unroll
        for (int o = 32; o > 0; o >>= 1) {
            float v2 = __shfl_down(v, o); int i2 = __shfl_down(id, o);
            if (v2 > v || (v2 == v && i2 < id)) { v = v2; id = i2; }
        }
        id = __shfl(id, 0);
        if (lane == id) cur = -3.4e38f;
        selI[k] = id;
        selR[k] = __shfl(r, id);
    }
    float s = 0.f;
    #pragma unroll
    for (int k = 0; k < K_TOP; ++k) s += selR[k];
    if (lane < K_TOP) {
        tki[t * K_TOP + lane] = selI[lane];
        tkw[t * K_TOP + lane] = selR[lane] / s;
        atomicAdd(&cnt[selI[lane]], 1);
    }
}

// parallel 64-lane exclusive scan
__global__ void scan_k(const int* __restrict__ cnt, int* __restrict__ offs, int* __restrict__ fill)
{
    int lane = threadIdx.x;          // 64
    int c = cnt[lane];
    int s = c;
    #pragma unroll
    for (int o = 1; o < 64; o <<= 1) {
        int v = __shfl_up(s, o);
        if (lane >= o) s += v;
    }
    int excl = s - c;
    offs[lane] = excl;
    fill[lane] = excl;
    if (lane == 63) offs[N_EXP] = s;
}

__global__ void fill_k(const int* __restrict__ tki, const float* __restrict__ tkw,
                       int* __restrict__ fill, int* __restrict__ atok, float* __restrict__ aw)
{
    int t = blockIdx.x, lane = threadIdx.x;
    if (lane < K_TOP) {
        int e = tki[t * K_TOP + lane];
        int p = atomicAdd(&fill[e], 1);
        atok[p] = t;
        aw[p] = tkw[t * K_TOP + lane];
    }
}

// ---------------- merged weight convert to MFMA-fragment-packed bf16 (ONE launch) ----------------
// frag layout per mat: offset_u16 = (n_tile*(K/32) + kb)*512 + lane*8; elem j of lane l =
//   W[kb*32 + (l>>4)*8 + j][n_tile*16 + (l&15)]   (B-operand layout)
__global__ __launch_bounds__(256) void convAll_k(
    const float* __restrict__ rW1, const float* __restrict__ sW1,
    const float* __restrict__ rW2, const float* __restrict__ sW2,
    const float* __restrict__ rWg, const float* __restrict__ sWg,
    u16* __restrict__ W1f, u16* __restrict__ W2f, u16* __restrict__ Wgf)
{
    int id = blockIdx.x;
    const float* src; u16* dst;
    int K, N, n0, k0;
    const size_t MS = (size_t)H_DIM * D_DIM;     // 524288
    if (id < 66 * 128) {
        int mat = id >> 7, tile = id & 127;
        K = D_DIM; N = H_DIM;
        src = (mat < N_EXP ? rW1 + (size_t)mat * MS : sW1 + (size_t)(mat - N_EXP) * MS);
        dst = W1f + (size_t)mat * MS;
        n0 = (tile & 7) << 6; k0 = (tile >> 3) << 6;
    } else if (id < 2 * 66 * 128) {
        id -= 66 * 128;
        int mat = id >> 7, tile = id & 127;
        K = H_DIM; N = D_DIM;
        src = (mat < N_EXP ? rW2 + (size_t)mat * MS : sW2 + (size_t)(mat - N_EXP) * MS);
        dst = W2f + (size_t)mat * MS;
        n0 = (tile & 15) << 6; k0 = (tile >> 4) << 6;
    } else {
        id -= 2 * 66 * 128;
        int mat = id >> 6, tile = id & 63;
        K = H_DIM; N = H_DIM;
        src = (mat == 0 ? rWg : sWg);
        dst = Wgf + (size_t)mat * (H_DIM * H_DIM);
        n0 = (tile & 7) << 6; k0 = (tile >> 3) << 6;
    }

    __shared__ u16 t[64][72];          // [n_local][k_local]
    int tid = threadIdx.x;
    int kr = tid >> 4, c4 = (tid & 15) << 2;
    #pragma unroll
    for (int rr = 0; rr < 4; ++rr) {
        int k = (rr << 4) + kr;
        float4 v = *(const float4*)(src + (size_t)(k0 + k) * N + n0 + c4);
        t[c4 + 0][k] = f2bf(v.x);
        t[c4 + 1][k] = f2bf(v.y);
        t[c4 + 2][k] = f2bf(v.z);
        t[c4 + 3][k] = f2bf(v.w);
    }
    __syncthreads();
    int lane = tid & 63, g = tid >> 6;
    int nr = lane & 15, kq = lane >> 4;
    #pragma unroll
    for (int f = 0; f < 2; ++f) {
        int fragId = g + (f << 2);                 // (n_tile 0..3) x (kb 0..1)
        int ntile = fragId >> 1, kb = fragId & 1;
        bh8 v = *(const bh8*)&t[(ntile << 4) + nr][(kb << 5) + (kq << 3)];
        size_t fi = (((size_t)((n0 >> 4) + ntile) * (size_t)(K >> 5)
                      + (size_t)((k0 >> 5) + kb)) << 9) + (size_t)(lane << 3);
        *(bh8*)(dst + fi) = v;
    }
}

// ===== shared decode for expert-aligned row slabs (p1/p3) =====
// bx in [0, 4608): xcd=bx&7, grp, slab. grp<8: routed e=grp*8+xcd; grp==8: shared.
// Returns false if no work.
__device__ __forceinline__ bool slabDecode(
    int bx, const int* __restrict__ offs,
    int& e, int& rowBase, int& rows, int& tokBase)
{
    int xcd = bx & 7, rest = bx >> 3, grp = rest >> 6, slab = rest & 63;
    if (grp < 8) {
        e = (grp << 3) + xcd;
        int s0 = offs[e], s1 = offs[e + 1];
        rowBase = s0 + (slab << 5);
        if (rowBase >= s1) return false;
        rows = s1 - rowBase; if (rows > 32) rows = 32;
        tokBase = -1;
        return true;
    }
    int f = (slab << 3) + xcd;
    if (f >= 128) return false;
    int sh = f & 1;
    e = N_EXP + sh;
    tokBase = (f >> 1) << 5;
    rowBase = N_ASG + (sh << 11) + tokBase;
    rows = 32;
    return true;
}

// ===== phase 1: h[r][512] = xnb[tok(r)] @ W1[e] + b1[e]  (K=1024) =====
// grid (4608, 2); 4 waves; wave tile 32 rows x 64 cols; TLP-heavy (16 waves/CU).
__global__ __launch_bounds__(256, 4) void p1_k(
    const u16* __restrict__ xnb, const u16* __restrict__ W1f,
    const float* __restrict__ rb1, const float* __restrict__ sb1,
    const int* __restrict__ offs, const int* __restrict__ atok,
    u16* __restrict__ h)
{
    int e, rowBase, rows, tokBase;
    if (!slabDecode(blockIdx.x, offs, e, rowBase, rows, tokBase)) return;

    __shared__ int tok[32];
    int tid = threadIdx.x;
    if (tid < 32) {
        int cl = tid < rows ? tid : rows - 1;
        tok[tid] = (tokBase < 0) ? atok[rowBase + cl] : tokBase + tid;
    }
    __syncthreads();

    int w = tid >> 6, lane = tid & 63, quad = lane >> 4, l15 = lane & 15;
    int cg = blockIdx.y;
    int nt0 = (cg << 4) + (w << 2);                 // ntile in [0,32)
    const u16* bp = W1f + (size_t)e * (H_DIM * D_DIM)
                  + (((size_t)nt0 << 5) << 9) + (lane << 3);
    const u16* a0p = xnb + (size_t)tok[l15] * D_DIM + (quad << 3);
    const u16* a1p = xnb + (size_t)tok[16 + l15] * D_DIM + (quad << 3);
    const float* b1 = (tokBase < 0) ? rb1 + e * H_DIM : sb1 + (e - N_EXP) * H_DIM;

    fx4 ac0[4] = {}, ac1[4] = {};
    bh8 bA[4], bB[4], aA0, aA1, aB0, aB1;
    #pragma unroll
    for (int ct = 0; ct < 4; ++ct) bA[ct] = *(const bh8*)(bp + ((size_t)(ct << 5) << 9));
    aA0 = *(const bh8*)a0p; aA1 = *(const bh8*)a1p;
    #pragma unroll 1
    for (int kb = 0; kb < 32; kb += 2) {
        #pragma unroll
        for (int ct = 0; ct < 4; ++ct) bB[ct] = *(const bh8*)(bp + (((ct << 5) + kb + 1) << 9));
        aB0 = *(const bh8*)(a0p + ((kb + 1) << 5));
        aB1 = *(const bh8*)(a1p + ((kb + 1) << 5));
        #pragma unroll
        for (int ct = 0; ct < 4; ++ct) {
            ac0[ct] = __builtin_amdgcn_mfma_f32_16x16x32_bf16(aA0, bA[ct], ac0[ct], 0, 0, 0);
            ac1[ct] = __builtin_amdgcn_mfma_f32_16x16x32_bf16(aA1, bA[ct], ac1[ct], 0, 0, 0);
        }
        #pragma unroll
        for (int ct = 0; ct < 4; ++ct) bA[ct] = *(const bh8*)(bp + (((ct << 5) + kb + 2) << 9));
        aA0 = *(const bh8*)(a0p + ((kb + 2) << 5));     // last iter overrun: valid ws memory
        aA1 = *(const bh8*)(a1p + ((kb + 2) << 5));
        #pragma unroll
        for (int ct = 0; ct < 4; ++ct) {
            ac0[ct] = __builtin_amdgcn_mfma_f32_16x16x32_bf16(aB0, bB[ct], ac0[ct], 0, 0, 0);
            ac1[ct] = __builtin_amdgcn_mfma_f32_16x16x32_bf16(aB1, bB[ct], ac1[ct], 0, 0, 0);
        }
    }
    #pragma unroll
    for (int ct = 0; ct < 4; ++ct) {
        int col = ((nt0 + ct) << 4) + l15;
        float bv = b1[col];
        #pragma unroll
        for (int r = 0; r < 4; ++r) {
            int r0 = (quad << 2) + r;
            if (r0 < rows) h[(size_t)(rowBase + r0) * H_DIM + col] = f2bf(ac0[ct][r] + bv);
            int r1 = 16 + r0;
            if (r1 < rows) h[(size_t)(rowBase + r1) * H_DIM + col] = f2bf(ac1[ct][r] + bv);
        }
    }
}

// ===== phase 2: hg[r] = h[r] * silu(h[r] @ Wg)  (K=512) =====
// grid (512, 2); rows direct (no expert gather). Wg = routed for r<12288 else shared.
__global__ __launch_bounds__(256, 4) void p2_k(
    const u16* __restrict__ hbuf, const u16* __restrict__ Wgf, u16* __restrict__ hg)
{
    int rowBase = blockIdx.x << 5;
    int tid = threadIdx.x;
    int w = tid >> 6, lane = tid & 63, quad = lane >> 4, l15 = lane & 15;
    int cg = blockIdx.y;
    int nt0 = (cg << 4) + (w << 2);
    const u16* bp = Wgf + (rowBase < N_ASG ? 0 : (size_t)(H_DIM * H_DIM))
                  + (((size_t)nt0 << 4) << 9) + (lane << 3);
    const u16* a0p = hbuf + (size_t)(rowBase + l15) * H_DIM + (quad << 3);
    const u16* a1p = hbuf + (size_t)(rowBase + 16 + l15) * H_DIM + (quad << 3);

    fx4 ac0[4] = {}, ac1[4] = {};
    bh8 bA[4], bB[4], aA0, aA1, aB0, aB1;
    #pragma unroll
    for (int ct = 0; ct < 4; ++ct) bA[ct] = *(const bh8*)(bp + ((size_t)(ct << 4) << 9));
    aA0 = *(const bh8*)a0p; aA1 = *(const bh8*)a1p;
    #pragma unroll 1
    for (int kb = 0; kb < 16; kb += 2) {
        #pragma unroll
        for (int ct = 0; ct < 4; ++ct) bB[ct] = *(const bh8*)(bp + (((ct << 4) + kb + 1) << 9));
        aB0 = *(const bh8*)(a0p + ((kb + 1) << 5));
        aB1 = *(const bh8*)(a1p + ((kb + 1) << 5));
        #pragma unroll
        for (int ct = 0; ct < 4; ++ct) {
            ac0[ct] = __builtin_amdgcn_mfma_f32_16x16x32_bf16(aA0, bA[ct], ac0[ct], 0, 0, 0);
            ac1[ct] = __builtin_amdgcn_mfma_f32_16x16x32_bf16(aA1, bA[ct], ac1[ct], 0, 0, 0);
        }
        #pragma unroll
        for (int ct = 0; ct < 4; ++ct) bA[ct] = *(const bh8*)(bp + (((ct << 4) + kb + 2) << 9));
        aA0 = *(const bh8*)(a0p + ((kb + 2) << 5));
        aA1 = *(const bh8*)(a1p + ((kb + 2) << 5));
        #pragma unroll
        for (int ct = 0; ct < 4; ++ct) {
            ac0[ct] = __builtin_amdgcn_mfma_f32_16x16x32_bf16(aB0, bB[ct], ac0[ct], 0, 0, 0);
            ac1[ct] = __builtin_amdgcn_mfma_f32_16x16x32_bf16(aB1, bB[ct], ac1[ct], 0, 0, 0);
        }
    }
    #pragma unroll
    for (int ct = 0; ct < 4; ++ct) {
        int col = ((nt0 + ct) << 4) + l15;
        #pragma unroll
        for (int r = 0; r < 4; ++r) {
            int r0 = (quad << 2) + r;
            size_t i0 = (size_t)(rowBase + r0) * H_DIM + col;
            float g0 = ac0[ct][r], h0 = bf2f(hbuf[i0]);
            hg[i0] = f2bf(h0 * g0 * (1.f / (1.f + __expf(-g0))));
            int r1 = 16 + r0;
            size_t i1 = (size_t)(rowBase + r1) * H_DIM + col;
            float g1 = ac1[ct][r], h1 = bf2f(hbuf[i1]);
            hg[i1] = f2bf(h1 * g1 * (1.f / (1.f + __expf(-g1))));
        }
    }
}

// ===== phase 3: acc[tok(r)] += wt(r) * (hg[r] @ W2[e] + b2[e])  (K=512, N=1024) =====
// grid (4608, 4)
__global__ __launch_bounds__(256, 4) void p3_k(
    const u16* __restrict__ hg, const u16* __restrict__ W2f,
    const float* __restrict__ rb2, const float* __restrict__ sb2,
    const int* __restrict__ offs, const int* __restrict__ atok,
    const float* __restrict__ aw, float* __restrict__ accG)
{
    int e, rowBase, rows, tokBase;
    if (!slabDecode(blockIdx.x, offs, e, rowBase, rows, tokBase)) return;

    __shared__ int tok[32];
    __shared__ float wt[32];
    int tid = threadIdx.x;
    if (tid < 32) {
        int cl = tid < rows ? tid : rows - 1;
        if (tokBase < 0) { tok[tid] = atok[rowBase + cl]; wt[tid] = aw[rowBase + cl]; }
        else             { tok[tid] = tokBase + tid;      wt[tid] = 1.0f; }
    }
    __syncthreads();

    int w = tid >> 6, lane = tid & 63, quad = lane >> 4, l15 = lane & 15;
    int cg = blockIdx.y;
    int nt0 = (cg << 4) + (w << 2);                 // ntile in [0,64)
    const u16* bp = W2f + (size_t)e * (H_DIM * D_DIM)
                  + (((size_t)nt0 << 4) << 9) + (lane << 3);
    const u16* a0p = hg + (size_t)(rowBase + l15) * H_DIM + (quad << 3);
    const u16* a1p = hg + (size_t)(rowBase + 16 + l15) * H_DIM + (quad << 3);
    const float* b2 = (tokBase < 0) ? rb2 + e * D_DIM : sb2 + (e - N_EXP) * D_DIM;

    fx4 ac0[4] = {}, ac1[4] = {};
    bh8 bA[4], bB[4], aA0, aA1, aB0, aB1;
    #pragma unroll
    for (int ct = 0; ct < 4; ++ct) bA[ct] = *(const bh8*)(bp + ((size_t)(ct << 4) << 9));
    aA0 = *(const bh8*)a0p; aA1 = *(const bh8*)a1p;
    #pragma unroll 1
    for (int kb = 0; kb < 16; kb += 2) {
        #pragma unroll
        for (int ct = 0; ct < 4; ++ct) bB[ct] = *(const bh8*)(bp + (((ct << 4) + kb + 1) << 9));
        aB0 = *(const bh8*)(a0p + ((kb + 1) << 5));
        aB1 = *(const bh8*)(a1p + ((kb + 1) << 5));
        #pragma unroll
        for (int ct = 0; ct < 4; ++ct) {
            ac0[ct] = __builtin_amdgcn_mfma_f32_16x16x32_bf16(aA0, bA[ct], ac0[ct], 0, 0, 0);
            ac1[ct] = __builtin_amdgcn_mfma_f32_16x16x32_bf16(aA1, bA[ct], ac1[ct], 0, 0, 0);
        }
        #pragma unroll
        for (int ct = 0; ct < 4; ++ct) bA[ct] = *(const bh8*)(bp + (((ct << 4) + kb + 2) << 9));
        aA0 = *(const bh8*)(a0p + ((kb + 2) << 5));
        aA1 = *(const bh8*)(a1p + ((kb + 2) << 5));
        #pragma unroll
        for (int ct = 0; ct < 4; ++ct) {
            ac0[ct] = __builtin_amdgcn_mfma_f32_16x16x32_bf16(aB0, bB[ct], ac0[ct], 0, 0, 0);
            ac1[ct] = __builtin_amdgcn_mfma_f32_16x16x32_bf16(aB1, bB[ct], ac1[ct], 0, 0, 0);
        }
    }
    #pragma unroll
    for (int ct = 0; ct < 4; ++ct) {
        int col = ((nt0 + ct) << 4) + l15;
        float bv = b2[col];
        #pragma unroll
        for (int r = 0; r < 4; ++r) {
            int r0 = (quad << 2) + r;
            if (r0 < rows)
                atomicAdd(&accG[(size_t)tok[r0] * D_DIM + col], wt[r0] * (ac0[ct][r] + bv));
            int r1 = 16 + r0;
            if (r1 < rows)
                atomicAdd(&accG[(size_t)tok[r1] * D_DIM + col], wt[r1] * (ac1[ct][r] + bv));
        }
    }
}

// ============ fallback fused FFN (raw fp32 weights), used only if workspace too small ============
template<int ROUTED>
__global__ __launch_bounds__(256) void moe_ffn_k(
    const u16* __restrict__ xnb,
    const float* __restrict__ W1b, const float* __restrict__ Wg,
    const float* __restrict__ W2b,
    const float* __restrict__ b1b, const float* __restrict__ b2b,
    const int* __restrict__ offs, const int* __restrict__ atok,
    const float* __restrict__ aw, float* __restrict__ accG)
{
    int e = blockIdx.z;
    int start = ROUTED ? offs[e] : 0;
    int end   = ROUTED ? offs[e + 1] : T_TOK;
    int rowBase = start + (blockIdx.y << 5);
    if (rowBase >= end) return;
    int rows = end - rowBase; if (rows > 32) rows = 32;

    __shared__ int   tok[32];
    __shared__ float wt[32];
    __shared__ u16 hA[32 * 520];
    __shared__ u16 hG[32 * 520];
    __shared__ u16 As[32 * 32];
    __shared__ u16 Bs[64 * 36];

    int tid = threadIdx.x;
    if (tid < 32) {
        int cl = rowBase + tid; if (cl >= end) cl = end - 1;
        tok[tid] = ROUTED ? atok[cl] : cl;
        wt[tid]  = ROUTED ? aw[cl] : 1.0f;
    }
    __syncthreads();

    const float* W1 = W1b + (size_t)e * (D_DIM * H_DIM);
    const float* W2 = W2b + (size_t)e * (D_DIM * H_DIM);
    const float* b1 = b1b + e * H_DIM;
    const float* b2 = b2b + e * D_DIM;

    int w = tid >> 6, lane = tid & 63, quad = lane >> 4, l15 = lane & 15;
    int sr2 = tid >> 3, sc2 = (tid & 7) << 2;

    for (int nc = 0; nc < 8; ++nc) {
        int n0 = nc << 6;
        fx4 a0 = {}; fx4 a1 = {};
        for (int kc = 0; kc < 32; ++kc) {
            int kb = kc << 5;
            int2 av = *(const int2*)(xnb + (size_t)tok[sr2] * D_DIM + kb + sc2);
            const float* cp = W1 + n0 + lane;
            int kx = kb + (w << 3);
            u32 p[4];
            #pragma unroll
            for (int jj = 0; jj < 4; ++jj) {
                u32 lo = f2bf(cp[(size_t)(kx + 2 * jj) * H_DIM]);
                u32 hi = f2bf(cp[(size_t)(kx + 2 * jj + 1) * H_DIM]);
                p[jj] = lo | (hi << 16);
            }
            __syncthreads();
            *(int2*)&As[sr2 * 32 + sc2] = av;
            u16* bsw = &Bs[lane * 36 + (w << 3)];
            uint2 q0; q0.x = p[0]; q0.y = p[1];
            uint2 q1; q1.x = p[2]; q1.y = p[3];
            *(uint2*)bsw = q0;
            *(uint2*)(bsw + 4) = q1;
            __syncthreads();
            bh8 af0 = *(const bh8*)&As[l15 * 32 + (quad << 3)];
            bh8 af1 = *(const bh8*)&As[(16 + l15) * 32 + (quad << 3)];
            const u16* brp = &Bs[((w << 4) + l15) * 36 + (quad << 3)];
            union { bh8 v; uint2 u2[2]; } bf;
            bf.u2[0] = *(const uint2*)brp;
            bf.u2[1] = *(const uint2*)(brp + 4);
            a0 = __builtin_amdgcn_mfma_f32_16x16x32_bf16(af0, bf.v, a0, 0, 0, 0);
            a1 = __builtin_amdgcn_mfma_f32_16x16x32_bf16(af1, bf.v, a1, 0, 0, 0);
        }
        int col = n0 + (w << 4) + l15;
        float bv = b1[col];
        #pragma unroll
        for (int r = 0; r < 4; ++r) {
            hA[((quad << 2) + r) * 520 + col]      = f2bf(a0[r] + bv);
            hA[(16 + (quad << 2) + r) * 520 + col] = f2bf(a1[r] + bv);
        }
    }
    __syncthreads();

    for (int nc = 0; nc < 8; ++nc) {
        int n0 = nc << 6;
        fx4 a0 = {}; fx4 a1 = {};
        for (int kc = 0; kc < 16; ++kc) {
            int kb = kc << 5;
            const float* cp = Wg + n0 + lane;
            int kx = kb + (w << 3);
            u32 p[4];
            #pragma unroll
            for (int jj = 0; jj < 4; ++jj) {
                u32 lo = f2bf(cp[(size_t)(kx + 2 * jj) * H_DIM]);
                u32 hi = f2bf(cp[(size_t)(kx + 2 * jj + 1) * H_DIM]);
                p[jj] = lo | (hi << 16);
            }
            __syncthreads();
            u16* bsw = &Bs[lane * 36 + (w << 3)];
            uint2 q0; q0.x = p[0]; q0.y = p[1];
            uint2 q1; q1.x = p[2]; q1.y = p[3];
            *(uint2*)bsw = q0;
            *(uint2*)(bsw + 4) = q1;
            __syncthreads();
            bh8 af0 = *(const bh8*)&hA[l15 * 520 + kb + (quad << 3)];
            bh8 af1 = *(const bh8*)&hA[(16 + l15) * 520 + kb + (quad << 3)];
            const u16* brp = &Bs[((w << 4) + l15) * 36 + (quad << 3)];
            union { bh8 v; uint2 u2[2]; } bf;
            bf.u2[0] = *(const uint2*)brp;
            bf.u2[1] = *(const uint2*)(brp + 4);
            a0 = __builtin_amdgcn_mfma_f32_16x16x32_bf16(af0, bf.v, a0, 0, 0, 0);
            a1 = __builtin_amdgcn_mfma_f32_16x16x32_bf16(af1, bf.v, a1, 0, 0, 0);
        }
        int col = n0 + (w << 4) + l15;
        #pragma unroll
        for (int r = 0; r < 4; ++r) {
            int r0 = (quad << 2) + r;
            float h0 = bf2f(hA[r0 * 520 + col]);
            float g0 = a0[r];
            hG[r0 * 520 + col] = f2bf(h0 * g0 * (1.f / (1.f + __expf(-g0))));
            int r1 = 16 + r0;
            float h1 = bf2f(hA[r1 * 520 + col]);
            float g1 = a1[r];
            hG[r1 * 520 + col] = f2bf(h1 * g1 * (1.f / (1.f + __expf(-g1))));
        }
    }
    __syncthreads();

    for (int nc = 0; nc < 16; ++nc) {
        int n0 = nc << 6;
        fx4 a0 = {}; fx4 a1 = {};
        for (int kc = 0; kc < 16; ++kc) {
            int kb = kc << 5;
            const float* cp = W2 + n0 + lane;
            int kx = kb + (w << 3);
            u32 p[4];
            #pragma unroll
            for (int jj = 0; jj < 4; ++jj) {
                u32 lo = f2bf(cp[(size_t)(kx + 2 * jj) * D_DIM]);
                u32 hi = f2bf(cp[(size_t)(kx + 2 * jj + 1) * D_DIM]);
                p[jj] = lo | (hi << 16);
            }
            __syncthreads();
            u16* bsw = &Bs[lane * 36 + (w << 3)];
            uint2 q0; q0.x = p[0]; q0.y = p[1];
            uint2 q1; q1.x = p[2]; q1.y = p[3];
            *(uint2*)bsw = q0;
            *(uint2*)(bsw + 4) = q1;
            __syncthreads();
            bh8 af0 = *(const bh8*)&hG[l15 * 520 + kb + (quad << 3)];
            bh8 af1 = *(const bh8*)&hG[(16 + l15) * 520 + kb + (quad << 3)];
            const u16* brp = &Bs[((w << 4) + l15) * 36 + (quad << 3)];
            union { bh8 v; uint2 u2[2]; } bf;
            bf.u2[0] = *(const uint2*)brp;
            bf.u2[1] = *(const uint2*)(brp + 4);
            a0 = __builtin_amdgcn_mfma_f32_16x16x32_bf16(af0, bf.v, a0, 0, 0, 0);
            a1 = __builtin_amdgcn_mfma_f32_16x16x32_bf16(af1, bf.v, a1, 0, 0, 0);
        }
        int col = n0 + (w << 4) + l15;
        float bv = b2[col];
        #pragma unroll
        for (int r = 0; r < 4; ++r) {
            int lr0 = (quad << 2) + r;
            if (lr0 < rows)
                atomicAdd(&accG[(size_t)tok[lr0] * D_DIM + col], wt[lr0] * (a0[r] + bv));
            int lr1 = 16 + lr0;
            if (lr1 < rows)
                atomicAdd(&accG[(size_t)tok[lr1] * D_DIM + col], wt[lr1] * (a1[r] + bv));
        }
    }
}

// ---------------- final: out = x + acc (all fp32) ----------------
__global__ __launch_bounds__(256) void final_k(
    const float* __restrict__ x, const float* __restrict__ acc, float* __restrict__ out)
{
    size_t i = ((size_t)blockIdx.x * 256 + threadIdx.x) << 2;
    float4 xv = *(const float4*)(x + i);
    float4 a = *(const float4*)(acc + i);
    float4 o;
    o.x = xv.x + a.x;
    o.y = xv.y + a.y;
    o.z = xv.z + a.z;
    o.w = xv.w + a.w;
    *(float4*)(out + i) = o;
}

extern "C" void kernel_launch(void* const* d_in, const int* in_sizes, int n_in,
                              void* d_out, int out_size, void* d_ws, size_t ws_size,
                              hipStream_t stream)
{
    const float* x     = (const float*)d_in[0];
    const float* nw    = (const float*)d_in[1];
    const float* Wr    = (const float*)d_in[2];
    const float* sW1   = (const float*)d_in[3];
    const float* sb1   = (const float*)d_in[4];
    const float* sW2   = (const float*)d_in[5];
    const float* sb2   = (const float*)d_in[6];
    const float* sWg   = (const float*)d_in[7];
    const float* rW1   = (const float*)d_in[8];
    const float* rb1   = (const float*)d_in[9];
    const float* rW2   = (const float*)d_in[10];
    const float* rb2   = (const float*)d_in[11];
    const float* rWg   = (const float*)d_in[12];
    const float* ebias = (const float*)d_in[13];
    float* out = (float*)d_out;
    (void)in_sizes; (void)n_in; (void)out_size;

    char* wp = (char*)d_ws;
    auto alloc = [&](size_t b) { char* p = wp; wp += (b + 255) & ~(size_t)255; return p; };
    int*   cnt  = (int*)alloc(N_EXP * 4);
    int*   offs = (int*)alloc((N_EXP + 1) * 4);
    int*   fill = (int*)alloc(N_EXP * 4);
    int*   tki  = (int*)alloc((size_t)T_TOK * K_TOP * 4);
    float* tkw  = (float*)alloc((size_t)T_TOK * K_TOP * 4);
    int*   atok = (int*)alloc((size_t)N_ASG * 4);
    float* aw   = (float*)alloc((size_t)N_ASG * 4);
    float* raw  = (float*)alloc((size_t)T_TOK * N_EXP * 4);
    u16*   xnb  = (u16*)alloc((size_t)T_TOK * D_DIM * 2);
    float* acc  = (float*)alloc((size_t)T_TOK * D_DIM * 4);
    // fast-path: fragment-packed bf16 weights + global h/hg
    u16* W1f = (u16*)alloc((size_t)(N_EXP + 2) * H_DIM * D_DIM * 2);
    u16* W2f = (u16*)alloc((size_t)(N_EXP + 2) * H_DIM * D_DIM * 2);
    u16* Wgf = (u16*)alloc((size_t)2 * H_DIM * H_DIM * 2);
    u16* h   = (u16*)alloc((size_t)R_TOT * H_DIM * 2);
    u16* hg  = (u16*)alloc((size_t)R_TOT * H_DIM * 2);
    alloc(1 << 16);   // slack pad: prefetch overruns land here, never used
    bool fast = (size_t)(wp - (char*)d_ws) <= ws_size;

    hipMemsetAsync(cnt, 0, N_EXP * 4, stream);
    hipMemsetAsync(acc, 0, (size_t)T_TOK * D_DIM * 4, stream);

    dim3 b256(256);
    rn4_k<<<T_TOK / 4, b256, 0, stream>>>(x, nw, Wr, raw, xnb);
    topk_k<<<T_TOK, dim3(64), 0, stream>>>(raw, ebias, cnt, tki, tkw);
    scan_k<<<1, dim3(64), 0, stream>>>(cnt, offs, fill);
    fill_k<<<T_TOK, dim3(64), 0, stream>>>(tki, tkw, fill, atok, aw);

    if (fast) {
        convAll_k<<<dim3(2 * 66 * 128 + 2 * 64), b256, 0, stream>>>(
            rW1, sW1, rW2, sW2, rWg, sWg, W1f, W2f, Wgf);

        p1_k<<<dim3(GRID_E, 2), b256, 0, stream>>>(xnb, W1f, rb1, sb1, offs, atok, h);
        p2_k<<<dim3(R_TOT / 32, 2), b256, 0, stream>>>(h, Wgf, hg);
        p3_k<<<dim3(GRID_E, 4), b256, 0, stream>>>(hg, W2f, rb2, sb2, offs, atok, aw, acc);
    } else {
        moe_ffn_k<1><<<dim3(1, 64, N_EXP), b256, 0, stream>>>(
            xnb, rW1, rWg, rW2, rb1, rb2, offs, atok, aw, acc);
        moe_ffn_k<0><<<dim3(1, 64, 2), b256, 0, stream>>>(
            xnb, sW1, sWg, sW2, sb1, sb2, offs, atok, aw, acc);
    }

    final_k<<<(T_TOK * D_DIM) / 1024, b256, 0, stream>>>(x, acc, out);
}

// Round 7
// 638.639 us; speedup vs baseline: 1.3381x; 1.0204x over previous
//
#include <hip/hip_runtime.h>
#include <cstdint>
#include <cstddef>

typedef unsigned short u16;
typedef unsigned int u32;
typedef __attribute__((ext_vector_type(8))) short bh8;
typedef __attribute__((ext_vector_type(4))) float fx4;

#define T_TOK 2048
#define D_DIM 1024
#define H_DIM 512
#define N_EXP 64
#define K_TOP 6
#define N_ASG (T_TOK * K_TOP)       // 12288
#define R_TOT (N_ASG + 2 * T_TOK)   // 16384 rows in h-space
#define GRID_E (8 * 9 * 64)         // 4608

__device__ __forceinline__ float bf2f(u16 v) {
    union { u32 u; float f; } c; c.u = ((u32)v) << 16; return c.f;
}
__device__ __forceinline__ u16 f2bf(float f) {
    union { u32 u; float f; } c; c.f = f;
    u32 u = c.u;
    return (u16)((u + 0x7fffu + ((u >> 16) & 1u)) >> 16);
}

// ---------------- fused RMSNorm + router, 4 tokens/block (Wr reuse x4) ----------------
__global__ __launch_bounds__(256) void rn4_k(
    const float* __restrict__ x, const float* __restrict__ nw,
    const float* __restrict__ Wr, float* __restrict__ raw, u16* __restrict__ xnb)
{
    int t0 = blockIdx.x << 2, tid = threadIdx.x;
    __shared__ float xs[4][D_DIM];
    __shared__ float ps[4][256];
    __shared__ float red4[4][4];
    int d0 = tid << 2;
    float4 wv = *(const float4*)(nw + d0);
    float4 xv[4];
    #pragma unroll
    for (int tt = 0; tt < 4; ++tt) {
        xv[tt] = *(const float4*)(x + (size_t)(t0 + tt) * D_DIM + d0);
        float ss = xv[tt].x * xv[tt].x + xv[tt].y * xv[tt].y
                 + xv[tt].z * xv[tt].z + xv[tt].w * xv[tt].w;
        #pragma unroll
        for (int o = 32; o > 0; o >>= 1) ss += __shfl_down(ss, o);
        if ((tid & 63) == 0) red4[tt][tid >> 6] = ss;
    }
    __syncthreads();
    #pragma unroll
    for (int tt = 0; tt < 4; ++tt) {
        float ms = (red4[tt][0] + red4[tt][1] + red4[tt][2] + red4[tt][3]) * (1.f / (float)D_DIM);
        float sc = rsqrtf(ms + 1.1920929e-07f);
        float4 xf;
        xf.x = xv[tt].x * sc * wv.x;
        xf.y = xv[tt].y * sc * wv.y;
        xf.z = xv[tt].z * sc * wv.z;
        xf.w = xv[tt].w * sc * wv.w;
        *(float4*)&xs[tt][d0] = xf;
        ushort4 ob;
        ob.x = f2bf(xf.x); ob.y = f2bf(xf.y); ob.z = f2bf(xf.z); ob.w = f2bf(xf.w);
        *(ushort4*)(xnb + (size_t)(t0 + tt) * D_DIM + d0) = ob;
    }
    __syncthreads();
    int e = tid & 63, part = tid >> 6;
    const float* wr = Wr + (size_t)e * D_DIM + part * 256;
    float s0 = 0.f, s1 = 0.f, s2 = 0.f, s3 = 0.f;
    const float* xp0 = &xs[0][part * 256];
    const float* xp1 = &xs[1][part * 256];
    const float* xp2 = &xs[2][part * 256];
    const float* xp3 = &xs[3][part * 256];
    #pragma unroll 4
    for (int i = 0; i < 256; i += 4) {
        float4 w4 = *(const float4*)(wr + i);
        s0 += xp0[i] * w4.x + xp0[i+1] * w4.y + xp0[i+2] * w4.z + xp0[i+3] * w4.w;
        s1 += xp1[i] * w4.x + xp1[i+1] * w4.y + xp1[i+2] * w4.z + xp1[i+3] * w4.w;
        s2 += xp2[i] * w4.x + xp2[i+1] * w4.y + xp2[i+2] * w4.z + xp2[i+3] * w4.w;
        s3 += xp3[i] * w4.x + xp3[i+1] * w4.y + xp3[i+2] * w4.z + xp3[i+3] * w4.w;
    }
    ps[0][tid] = s0; ps[1][tid] = s1; ps[2][tid] = s2; ps[3][tid] = s3;
    __syncthreads();
    if (part == 0) {
        #pragma unroll
        for (int tt = 0; tt < 4; ++tt)
            raw[(size_t)(t0 + tt) * N_EXP + e] =
                ps[tt][e] + ps[tt][64 + e] + ps[tt][128 + e] + ps[tt][192 + e];
    }
}

// ---------------- top-k (one wave per token), fp32 ----------------
__global__ void topk_k(const float* __restrict__ raw, const float* __restrict__ ebias,
                       int* __restrict__ cnt, int* __restrict__ tki, float* __restrict__ tkw)
{
    int t = blockIdx.x, lane = threadIdx.x;
    float r = raw[(size_t)t * N_EXP + lane];
    float cur = r + ebias[lane];
    int selI[K_TOP]; float selR[K_TOP];
    #pragma unroll
    for (int k = 0; k < K_TOP; ++k) {
        float v = cur; int id = lane;
        #pragma unroll
        for (int o = 32; o > 0; o >>= 1) {
            float v2 = __shfl_down(v, o); int i2 = __shfl_down(id, o);
            if (v2 > v || (v2 == v && i2 < id)) { v = v2; id = i2; }
        }
        id = __shfl(id, 0);
        if (lane == id) cur = -3.4e38f;
        selI[k] = id;
        selR[k] = __shfl(r, id);
    }
    float s = 0.f;
    #pragma unroll
    for (int k = 0; k < K_TOP; ++k) s += selR[k];
    if (lane < K_TOP) {
        tki[t * K_TOP + lane] = selI[lane];
        tkw[t * K_TOP + lane] = selR[lane] / s;
        atomicAdd(&cnt[selI[lane]], 1);
    }
}

// parallel 64-lane exclusive scan
__global__ void scan_k(const int* __restrict__ cnt, int* __restrict__ offs, int* __restrict__ fill)
{
    int lane = threadIdx.x;          // 64
    int c = cnt[lane];
    int s = c;
    #pragma unroll
    for (int o = 1; o < 64; o <<= 1) {
        int v = __shfl_up(s, o);
        if (lane >= o) s += v;
    }
    int excl = s - c;
    offs[lane] = excl;
    fill[lane] = excl;
    if (lane == 63) offs[N_EXP] = s;
}

__global__ void fill_k(const int* __restrict__ tki, const float* __restrict__ tkw,
                       int* __restrict__ fill, int* __restrict__ atok, float* __restrict__ aw,
                       int* __restrict__ rowOf)
{
    int t = blockIdx.x, lane = threadIdx.x;
    if (lane < K_TOP) {
        int e = tki[t * K_TOP + lane];
        int p = atomicAdd(&fill[e], 1);
        atok[p] = t;
        aw[p] = tkw[t * K_TOP + lane];
        rowOf[t * K_TOP + lane] = p;
    }
}

// ---------------- merged weight convert to MFMA-fragment-packed bf16 (ONE launch) ----------------
// LDS tile stride 68 u16: write stride 136 dw === 8 (mod 32) -> 4-way;
// read stride 34 dw === 2 -> 2-way (free). Was [64][72]: 8-way on writes (15.8M conflicts).
__global__ __launch_bounds__(256) void convAll_k(
    const float* __restrict__ rW1, const float* __restrict__ sW1,
    const float* __restrict__ rW2, const float* __restrict__ sW2,
    const float* __restrict__ rWg, const float* __restrict__ sWg,
    u16* __restrict__ W1f, u16* __restrict__ W2f, u16* __restrict__ Wgf)
{
    int id = blockIdx.x;
    const float* src; u16* dst;
    int K, N, n0, k0;
    const size_t MS = (size_t)H_DIM * D_DIM;     // 524288
    if (id < 66 * 128) {
        int mat = id >> 7, tile = id & 127;
        K = D_DIM; N = H_DIM;
        src = (mat < N_EXP ? rW1 + (size_t)mat * MS : sW1 + (size_t)(mat - N_EXP) * MS);
        dst = W1f + (size_t)mat * MS;
        n0 = (tile & 7) << 6; k0 = (tile >> 3) << 6;
    } else if (id < 2 * 66 * 128) {
        id -= 66 * 128;
        int mat = id >> 7, tile = id & 127;
        K = H_DIM; N = D_DIM;
        src = (mat < N_EXP ? rW2 + (size_t)mat * MS : sW2 + (size_t)(mat - N_EXP) * MS);
        dst = W2f + (size_t)mat * MS;
        n0 = (tile & 15) << 6; k0 = (tile >> 4) << 6;
    } else {
        id -= 2 * 66 * 128;
        int mat = id >> 6, tile = id & 63;
        K = H_DIM; N = H_DIM;
        src = (mat == 0 ? rWg : sWg);
        dst = Wgf + (size_t)mat * (H_DIM * H_DIM);
        n0 = (tile & 7) << 6; k0 = (tile >> 3) << 6;
    }

    __shared__ u16 t[64][68];          // [n_local][k_local], pad 68
    int tid = threadIdx.x;
    int kr = tid >> 4, c4 = (tid & 15) << 2;
    #pragma unroll
    for (int rr = 0; rr < 4; ++rr) {
        int k = (rr << 4) + kr;
        float4 v = *(const float4*)(src + (size_t)(k0 + k) * N + n0 + c4);
        t[c4 + 0][k] = f2bf(v.x);
        t[c4 + 1][k] = f2bf(v.y);
        t[c4 + 2][k] = f2bf(v.z);
        t[c4 + 3][k] = f2bf(v.w);
    }
    __syncthreads();
    int lane = tid & 63, g = tid >> 6;
    int nr = lane & 15, kq = lane >> 4;
    #pragma unroll
    for (int f = 0; f < 2; ++f) {
        int fragId = g + (f << 2);                 // (n_tile 0..3) x (kb 0..1)
        int ntile = fragId >> 1, kb = fragId & 1;
        bh8 v = *(const bh8*)&t[(ntile << 4) + nr][(kb << 5) + (kq << 3)];
        size_t fi = (((size_t)((n0 >> 4) + ntile) * (size_t)(K >> 5)
                      + (size_t)((k0 >> 5) + kb)) << 9) + (size_t)(lane << 3);
        *(bh8*)(dst + fi) = v;
    }
}

// ===== shared decode for expert-aligned row slabs (p1/p3) =====
__device__ __forceinline__ bool slabDecode(
    int bx, const int* __restrict__ offs,
    int& e, int& rowBase, int& rows, int& tokBase)
{
    int xcd = bx & 7, rest = bx >> 3, grp = rest >> 6, slab = rest & 63;
    if (grp < 8) {
        e = (grp << 3) + xcd;
        int s0 = offs[e], s1 = offs[e + 1];
        rowBase = s0 + (slab << 5);
        if (rowBase >= s1) return false;
        rows = s1 - rowBase; if (rows > 32) rows = 32;
        tokBase = -1;
        return true;
    }
    int f = (slab << 3) + xcd;
    if (f >= 128) return false;
    int sh = f & 1;
    e = N_EXP + sh;
    tokBase = (f >> 1) << 5;
    rowBase = N_ASG + (sh << 11) + tokBase;
    rows = 32;
    return true;
}

// ===== phase 1: h[r][512] = xnb[tok(r)] @ W1[e] + b1[e]  (K=1024) =====
__global__ __launch_bounds__(256, 4) void p1_k(
    const u16* __restrict__ xnb, const u16* __restrict__ W1f,
    const float* __restrict__ rb1, const float* __restrict__ sb1,
    const int* __restrict__ offs, const int* __restrict__ atok,
    u16* __restrict__ h)
{
    int e, rowBase, rows, tokBase;
    if (!slabDecode(blockIdx.x, offs, e, rowBase, rows, tokBase)) return;

    __shared__ int tok[32];
    int tid = threadIdx.x;
    if (tid < 32) {
        int cl = tid < rows ? tid : rows - 1;
        tok[tid] = (tokBase < 0) ? atok[rowBase + cl] : tokBase + tid;
    }
    __syncthreads();

    int w = tid >> 6, lane = tid & 63, quad = lane >> 4, l15 = lane & 15;
    int cg = blockIdx.y;
    int nt0 = (cg << 4) + (w << 2);                 // ntile in [0,32)
    const u16* bp = W1f + (size_t)e * (H_DIM * D_DIM)
                  + (((size_t)nt0 << 5) << 9) + (lane << 3);
    const u16* a0p = xnb + (size_t)tok[l15] * D_DIM + (quad << 3);
    const u16* a1p = xnb + (size_t)tok[16 + l15] * D_DIM + (quad << 3);
    const float* b1 = (tokBase < 0) ? rb1 + e * H_DIM : sb1 + (e - N_EXP) * H_DIM;

    fx4 ac0[4] = {}, ac1[4] = {};
    bh8 bA[4], bB[4], aA0, aA1, aB0, aB1;
    #pragma unroll
    for (int ct = 0; ct < 4; ++ct) bA[ct] = *(const bh8*)(bp + ((size_t)(ct << 5) << 9));
    aA0 = *(const bh8*)a0p; aA1 = *(const bh8*)a1p;
    #pragma unroll 1
    for (int kb = 0; kb < 32; kb += 2) {
        #pragma unroll
        for (int ct = 0; ct < 4; ++ct) bB[ct] = *(const bh8*)(bp + (((ct << 5) + kb + 1) << 9));
        aB0 = *(const bh8*)(a0p + ((kb + 1) << 5));
        aB1 = *(const bh8*)(a1p + ((kb + 1) << 5));
        #pragma unroll
        for (int ct = 0; ct < 4; ++ct) {
            ac0[ct] = __builtin_amdgcn_mfma_f32_16x16x32_bf16(aA0, bA[ct], ac0[ct], 0, 0, 0);
            ac1[ct] = __builtin_amdgcn_mfma_f32_16x16x32_bf16(aA1, bA[ct], ac1[ct], 0, 0, 0);
        }
        #pragma unroll
        for (int ct = 0; ct < 4; ++ct) bA[ct] = *(const bh8*)(bp + (((ct << 5) + kb + 2) << 9));
        aA0 = *(const bh8*)(a0p + ((kb + 2) << 5));     // last iter overrun: valid ws memory
        aA1 = *(const bh8*)(a1p + ((kb + 2) << 5));
        #pragma unroll
        for (int ct = 0; ct < 4; ++ct) {
            ac0[ct] = __builtin_amdgcn_mfma_f32_16x16x32_bf16(aB0, bB[ct], ac0[ct], 0, 0, 0);
            ac1[ct] = __builtin_amdgcn_mfma_f32_16x16x32_bf16(aB1, bB[ct], ac1[ct], 0, 0, 0);
        }
    }
    #pragma unroll
    for (int ct = 0; ct < 4; ++ct) {
        int col = ((nt0 + ct) << 4) + l15;
        float bv = b1[col];
        #pragma unroll
        for (int r = 0; r < 4; ++r) {
            int r0 = (quad << 2) + r;
            if (r0 < rows) h[(size_t)(rowBase + r0) * H_DIM + col] = f2bf(ac0[ct][r] + bv);
            int r1 = 16 + r0;
            if (r1 < rows) h[(size_t)(rowBase + r1) * H_DIM + col] = f2bf(ac1[ct][r] + bv);
        }
    }
}

// ===== phase 2: h[r] <- h[r] * silu(h[r] @ Wg), IN PLACE  (K=512) =====
// 16-row blocks (1024 blocks); each block owns its rows exclusively; barrier between
// the K-loop (reads all cols of own rows) and the in-place epilogue write.
__global__ __launch_bounds__(256, 4) void p2_k(
    u16* __restrict__ h, const u16* __restrict__ Wgf)
{
    int rowBase = blockIdx.x << 4;
    int tid = threadIdx.x;
    int w = tid >> 6, lane = tid & 63, quad = lane >> 4, l15 = lane & 15;
    const u16* bp = Wgf + (rowBase < N_ASG ? 0 : (size_t)(H_DIM * H_DIM)) + (lane << 3);
    const u16* a0p = h + (size_t)(rowBase + l15) * H_DIM + (quad << 3);

    fx4 ac[8] = {};
    bh8 bA[8], bB[8], aA, aB;
    #pragma unroll
    for (int ct = 0; ct < 8; ++ct)
        bA[ct] = *(const bh8*)(bp + ((((size_t)(w << 3) + ct) << 4) << 9));
    aA = *(const bh8*)a0p;
    #pragma unroll 1
    for (int kb = 0; kb < 16; kb += 2) {
        #pragma unroll
        for (int ct = 0; ct < 8; ++ct)
            bB[ct] = *(const bh8*)(bp + (((((size_t)(w << 3) + ct) << 4) + kb + 1) << 9));
        aB = *(const bh8*)(a0p + ((kb + 1) << 5));
        #pragma unroll
        for (int ct = 0; ct < 8; ++ct)
            ac[ct] = __builtin_amdgcn_mfma_f32_16x16x32_bf16(aA, bA[ct], ac[ct], 0, 0, 0);
        #pragma unroll
        for (int ct = 0; ct < 8; ++ct)
            bA[ct] = *(const bh8*)(bp + (((((size_t)(w << 3) + ct) << 4) + kb + 2) << 9));
        aA = *(const bh8*)(a0p + ((kb + 2) << 5));
        #pragma unroll
        for (int ct = 0; ct < 8; ++ct)
            ac[ct] = __builtin_amdgcn_mfma_f32_16x16x32_bf16(aB, bB[ct], ac[ct], 0, 0, 0);
    }
    __syncthreads();   // all reads of this block's rows complete before in-place write
    #pragma unroll
    for (int ct = 0; ct < 8; ++ct) {
        int col = (((w << 3) + ct) << 4) + l15;
        #pragma unroll
        for (int r = 0; r < 4; ++r) {
            int row = rowBase + (quad << 2) + r;
            size_t i = (size_t)row * H_DIM + col;
            float g = ac[ct][r], hv = bf2f(h[i]);
            h[i] = f2bf(hv * g * (1.f / (1.f + __expf(-g))));
        }
    }
}

// ===== phase 3: out rows = wt(r)*(hg[r] @ W2[e] + b2[e])  (K=512, N=1024) =====
// ATOM=1: atomicAdd into acc (fallback tier). ATOM=0: plain store into outAll.
template<int ATOM>
__global__ __launch_bounds__(256, 4) void p3_k(
    const u16* __restrict__ hg, const u16* __restrict__ W2f,
    const float* __restrict__ rb2, const float* __restrict__ sb2,
    const int* __restrict__ offs, const int* __restrict__ atok,
    const float* __restrict__ aw, float* __restrict__ accG, float* __restrict__ outAll)
{
    int e, rowBase, rows, tokBase;
    if (!slabDecode(blockIdx.x, offs, e, rowBase, rows, tokBase)) return;

    __shared__ int tok[32];
    __shared__ float wt[32];
    int tid = threadIdx.x;
    if (tid < 32) {
        int cl = tid < rows ? tid : rows - 1;
        if (tokBase < 0) { tok[tid] = atok[rowBase + cl]; wt[tid] = aw[rowBase + cl]; }
        else             { tok[tid] = tokBase + tid;      wt[tid] = 1.0f; }
    }
    __syncthreads();

    int w = tid >> 6, lane = tid & 63, quad = lane >> 4, l15 = lane & 15;
    int cg = blockIdx.y;
    int nt0 = (cg << 4) + (w << 2);                 // ntile in [0,64)
    const u16* bp = W2f + (size_t)e * (H_DIM * D_DIM)
                  + (((size_t)nt0 << 4) << 9) + (lane << 3);
    const u16* a0p = hg + (size_t)(rowBase + l15) * H_DIM + (quad << 3);
    const u16* a1p = hg + (size_t)(rowBase + 16 + l15) * H_DIM + (quad << 3);
    const float* b2 = (tokBase < 0) ? rb2 + e * D_DIM : sb2 + (e - N_EXP) * D_DIM;

    fx4 ac0[4] = {}, ac1[4] = {};
    bh8 bA[4], bB[4], aA0, aA1, aB0, aB1;
    #pragma unroll
    for (int ct = 0; ct < 4; ++ct) bA[ct] = *(const bh8*)(bp + ((size_t)(ct << 4) << 9));
    aA0 = *(const bh8*)a0p; aA1 = *(const bh8*)a1p;
    #pragma unroll 1
    for (int kb = 0; kb < 16; kb += 2) {
        #pragma unroll
        for (int ct = 0; ct < 4; ++ct) bB[ct] = *(const bh8*)(bp + (((ct << 4) + kb + 1) << 9));
        aB0 = *(const bh8*)(a0p + ((kb + 1) << 5));
        aB1 = *(const bh8*)(a1p + ((kb + 1) << 5));
        #pragma unroll
        for (int ct = 0; ct < 4; ++ct) {
            ac0[ct] = __builtin_amdgcn_mfma_f32_16x16x32_bf16(aA0, bA[ct], ac0[ct], 0, 0, 0);
            ac1[ct] = __builtin_amdgcn_mfma_f32_16x16x32_bf16(aA1, bA[ct], ac1[ct], 0, 0, 0);
        }
        #pragma unroll
        for (int ct = 0; ct < 4; ++ct) bA[ct] = *(const bh8*)(bp + (((ct << 4) + kb + 2) << 9));
        aA0 = *(const bh8*)(a0p + ((kb + 2) << 5));
        aA1 = *(const bh8*)(a1p + ((kb + 2) << 5));
        #pragma unroll
        for (int ct = 0; ct < 4; ++ct) {
            ac0[ct] = __builtin_amdgcn_mfma_f32_16x16x32_bf16(aB0, bB[ct], ac0[ct], 0, 0, 0);
            ac1[ct] = __builtin_amdgcn_mfma_f32_16x16x32_bf16(aB1, bB[ct], ac1[ct], 0, 0, 0);
        }
    }
    #pragma unroll
    for (int ct = 0; ct < 4; ++ct) {
        int col = ((nt0 + ct) << 4) + l15;
        float bv = b2[col];
        #pragma unroll
        for (int r = 0; r < 4; ++r) {
            int r0 = (quad << 2) + r;
            if (r0 < rows) {
                float v = wt[r0] * (ac0[ct][r] + bv);
                if (ATOM) atomicAdd(&accG[(size_t)tok[r0] * D_DIM + col], v);
                else      outAll[(size_t)(rowBase + r0) * D_DIM + col] = v;
            }
            int r1 = 16 + r0;
            if (r1 < rows) {
                float v = wt[r1] * (ac1[ct][r] + bv);
                if (ATOM) atomicAdd(&accG[(size_t)tok[r1] * D_DIM + col], v);
                else      outAll[(size_t)(rowBase + r1) * D_DIM + col] = v;
            }
        }
    }
}

// ---------------- gather: out[t] = x[t] + sum of 6 routed rows + 2 shared rows ----------------
__global__ __launch_bounds__(256) void gather_k(
    const float* __restrict__ x, const float* __restrict__ outAll,
    const int* __restrict__ rowOf, float* __restrict__ out)
{
    int t = blockIdx.x, tid = threadIdx.x;
    __shared__ int rws[K_TOP];
    if (tid < K_TOP) rws[tid] = rowOf[t * K_TOP + tid];
    __syncthreads();
    int d0 = tid << 2;
    size_t base = (size_t)t * D_DIM + d0;
    float4 xv = *(const float4*)(x + base);
    float4 s = *(const float4*)(outAll + (size_t)(N_ASG + t) * D_DIM + d0);
    float4 s1 = *(const float4*)(outAll + (size_t)(N_ASG + T_TOK + t) * D_DIM + d0);
    s.x += s1.x; s.y += s1.y; s.z += s1.z; s.w += s1.w;
    #pragma unroll
    for (int k = 0; k < K_TOP; ++k) {
        float4 v = *(const float4*)(outAll + (size_t)rws[k] * D_DIM + d0);
        s.x += v.x; s.y += v.y; s.z += v.z; s.w += v.w;
    }
    float4 o;
    o.x = xv.x + s.x; o.y = xv.y + s.y; o.z = xv.z + s.z; o.w = xv.w + s.w;
    *(float4*)(out + base) = o;
}

// ============ fallback fused FFN (raw fp32 weights), used only if workspace too small ============
template<int ROUTED>
__global__ __launch_bounds__(256) void moe_ffn_k(
    const u16* __restrict__ xnb,
    const float* __restrict__ W1b, const float* __restrict__ Wg,
    const float* __restrict__ W2b,
    const float* __restrict__ b1b, const float* __restrict__ b2b,
    const int* __restrict__ offs, const int* __restrict__ atok,
    const float* __restrict__ aw, float* __restrict__ accG)
{
    int e = blockIdx.z;
    int start = ROUTED ? offs[e] : 0;
    int end   = ROUTED ? offs[e + 1] : T_TOK;
    int rowBase = start + (blockIdx.y << 5);
    if (rowBase >= end) return;
    int rows = end - rowBase; if (rows > 32) rows = 32;

    __shared__ int   tok[32];
    __shared__ float wt[32];
    __shared__ u16 hA[32 * 520];
    __shared__ u16 hG[32 * 520];
    __shared__ u16 As[32 * 32];
    __shared__ u16 Bs[64 * 36];

    int tid = threadIdx.x;
    if (tid < 32) {
        int cl = rowBase + tid; if (cl >= end) cl = end - 1;
        tok[tid] = ROUTED ? atok[cl] : cl;
        wt[tid]  = ROUTED ? aw[cl] : 1.0f;
    }
    __syncthreads();

    const float* W1 = W1b + (size_t)e * (D_DIM * H_DIM);
    const float* W2 = W2b + (size_t)e * (D_DIM * H_DIM);
    const float* b1 = b1b + e * H_DIM;
    const float* b2 = b2b + e * D_DIM;

    int w = tid >> 6, lane = tid & 63, quad = lane >> 4, l15 = lane & 15;
    int sr2 = tid >> 3, sc2 = (tid & 7) << 2;

    for (int nc = 0; nc < 8; ++nc) {
        int n0 = nc << 6;
        fx4 a0 = {}; fx4 a1 = {};
        for (int kc = 0; kc < 32; ++kc) {
            int kb = kc << 5;
            int2 av = *(const int2*)(xnb + (size_t)tok[sr2] * D_DIM + kb + sc2);
            const float* cp = W1 + n0 + lane;
            int kx = kb + (w << 3);
            u32 p[4];
            #pragma unroll
            for (int jj = 0; jj < 4; ++jj) {
                u32 lo = f2bf(cp[(size_t)(kx + 2 * jj) * H_DIM]);
                u32 hi = f2bf(cp[(size_t)(kx + 2 * jj + 1) * H_DIM]);
                p[jj] = lo | (hi << 16);
            }
            __syncthreads();
            *(int2*)&As[sr2 * 32 + sc2] = av;
            u16* bsw = &Bs[lane * 36 + (w << 3)];
            uint2 q0; q0.x = p[0]; q0.y = p[1];
            uint2 q1; q1.x = p[2]; q1.y = p[3];
            *(uint2*)bsw = q0;
            *(uint2*)(bsw + 4) = q1;
            __syncthreads();
            bh8 af0 = *(const bh8*)&As[l15 * 32 + (quad << 3)];
            bh8 af1 = *(const bh8*)&As[(16 + l15) * 32 + (quad << 3)];
            const u16* brp = &Bs[((w << 4) + l15) * 36 + (quad << 3)];
            union { bh8 v; uint2 u2[2]; } bf;
            bf.u2[0] = *(const uint2*)brp;
            bf.u2[1] = *(const uint2*)(brp + 4);
            a0 = __builtin_amdgcn_mfma_f32_16x16x32_bf16(af0, bf.v, a0, 0, 0, 0);
            a1 = __builtin_amdgcn_mfma_f32_16x16x32_bf16(af1, bf.v, a1, 0, 0, 0);
        }
        int col = n0 + (w << 4) + l15;
        float bv = b1[col];
        #pragma unroll
        for (int r = 0; r < 4; ++r) {
            hA[((quad << 2) + r) * 520 + col]      = f2bf(a0[r] + bv);
            hA[(16 + (quad << 2) + r) * 520 + col] = f2bf(a1[r] + bv);
        }
    }
    __syncthreads();

    for (int nc = 0; nc < 8; ++nc) {
        int n0 = nc << 6;
        fx4 a0 = {}; fx4 a1 = {};
        for (int kc = 0; kc < 16; ++kc) {
            int kb = kc << 5;
            const float* cp = Wg + n0 + lane;
            int kx = kb + (w << 3);
            u32 p[4];
            #pragma unroll
            for (int jj = 0; jj < 4; ++jj) {
                u32 lo = f2bf(cp[(size_t)(kx + 2 * jj) * H_DIM]);
                u32 hi = f2bf(cp[(size_t)(kx + 2 * jj + 1) * H_DIM]);
                p[jj] = lo | (hi << 16);
            }
            __syncthreads();
            u16* bsw = &Bs[lane * 36 + (w << 3)];
            uint2 q0; q0.x = p[0]; q0.y = p[1];
            uint2 q1; q1.x = p[2]; q1.y = p[3];
            *(uint2*)bsw = q0;
            *(uint2*)(bsw + 4) = q1;
            __syncthreads();
            bh8 af0 = *(const bh8*)&hA[l15 * 520 + kb + (quad << 3)];
            bh8 af1 = *(const bh8*)&hA[(16 + l15) * 520 + kb + (quad << 3)];
            const u16* brp = &Bs[((w << 4) + l15) * 36 + (quad << 3)];
            union { bh8 v; uint2 u2[2]; } bf;
            bf.u2[0] = *(const uint2*)brp;
            bf.u2[1] = *(const uint2*)(brp + 4);
            a0 = __builtin_amdgcn_mfma_f32_16x16x32_bf16(af0, bf.v, a0, 0, 0, 0);
            a1 = __builtin_amdgcn_mfma_f32_16x16x32_bf16(af1, bf.v, a1, 0, 0, 0);
        }
        int col = n0 + (w << 4) + l15;
        #pragma unroll
        for (int r = 0; r < 4; ++r) {
            int r0 = (quad << 2) + r;
            float h0 = bf2f(hA[r0 * 520 + col]);
            float g0 = a0[r];
            hG[r0 * 520 + col] = f2bf(h0 * g0 * (1.f / (1.f + __expf(-g0))));
            int r1 = 16 + r0;
            float h1 = bf2f(hA[r1 * 520 + col]);
            float g1 = a1[r];
            hG[r1 * 520 + col] = f2bf(h1 * g1 * (1.f / (1.f + __expf(-g1))));
        }
    }
    __syncthreads();

    for (int nc = 0; nc < 16; ++nc) {
        int n0 = nc << 6;
        fx4 a0 = {}; fx4 a1 = {};
        for (int kc = 0; kc < 16; ++kc) {
            int kb = kc << 5;
            const float* cp = W2 + n0 + lane;
            int kx = kb + (w << 3);
            u32 p[4];
            #pragma unroll
            for (int jj = 0; jj < 4; ++jj) {
                u32 lo = f2bf(cp[(size_t)(kx + 2 * jj) * D_DIM]);
                u32 hi = f2bf(cp[(size_t)(kx + 2 * jj + 1) * D_DIM]);
                p[jj] = lo | (hi << 16);
            }
            __syncthreads();
            u16* bsw = &Bs[lane * 36 + (w << 3)];
            uint2 q0; q0.x = p[0]; q0.y = p[1];
            uint2 q1; q1.x = p[2]; q1.y = p[3];
            *(uint2*)bsw = q0;
            *(uint2*)(bsw + 4) = q1;
            __syncthreads();
            bh8 af0 = *(const bh8*)&hG[l15 * 520 + kb + (quad << 3)];
            bh8 af1 = *(const bh8*)&hG[(16 + l15) * 520 + kb + (quad << 3)];
            const u16* brp = &Bs[((w << 4) + l15) * 36 + (quad << 3)];
            union { bh8 v; uint2 u2[2]; } bf;
            bf.u2[0] = *(const uint2*)brp;
            bf.u2[1] = *(const uint2*)(brp + 4);
            a0 = __builtin_amdgcn_mfma_f32_16x16x32_bf16(af0, bf.v, a0, 0, 0, 0);
            a1 = __builtin_amdgcn_mfma_f32_16x16x32_bf16(af1, bf.v, a1, 0, 0, 0);
        }
        int col = n0 + (w << 4) + l15;
        float bv = b2[col];
        #pragma unroll
        for (int r = 0; r < 4; ++r) {
            int lr0 = (quad << 2) + r;
            if (lr0 < rows)
                atomicAdd(&accG[(size_t)tok[lr0] * D_DIM + col], wt[lr0] * (a0[r] + bv));
            int lr1 = 16 + lr0;
            if (lr1 < rows)
                atomicAdd(&accG[(size_t)tok[lr1] * D_DIM + col], wt[lr1] * (a1[r] + bv));
        }
    }
}

// ---------------- final (atomic tiers): out = x + acc ----------------
__global__ __launch_bounds__(256) void final_k(
    const float* __restrict__ x, const float* __restrict__ acc, float* __restrict__ out)
{
    size_t i = ((size_t)blockIdx.x * 256 + threadIdx.x) << 2;
    float4 xv = *(const float4*)(x + i);
    float4 a = *(const float4*)(acc + i);
    float4 o;
    o.x = xv.x + a.x;
    o.y = xv.y + a.y;
    o.z = xv.z + a.z;
    o.w = xv.w + a.w;
    *(float4*)(out + i) = o;
}

extern "C" void kernel_launch(void* const* d_in, const int* in_sizes, int n_in,
                              void* d_out, int out_size, void* d_ws, size_t ws_size,
                              hipStream_t stream)
{
    const float* x     = (const float*)d_in[0];
    const float* nw    = (const float*)d_in[1];
    const float* Wr    = (const float*)d_in[2];
    const float* sW1   = (const float*)d_in[3];
    const float* sb1   = (const float*)d_in[4];
    const float* sW2   = (const float*)d_in[5];
    const float* sb2   = (const float*)d_in[6];
    const float* sWg   = (const float*)d_in[7];
    const float* rW1   = (const float*)d_in[8];
    const float* rb1   = (const float*)d_in[9];
    const float* rW2   = (const float*)d_in[10];
    const float* rb2   = (const float*)d_in[11];
    const float* rWg   = (const float*)d_in[12];
    const float* ebias = (const float*)d_in[13];
    float* out = (float*)d_out;
    (void)in_sizes; (void)n_in; (void)out_size;

    char* wp = (char*)d_ws;
    auto alloc = [&](size_t b) { char* p = wp; wp += (b + 255) & ~(size_t)255; return p; };
    int*   cnt  = (int*)alloc(N_EXP * 4);
    int*   offs = (int*)alloc((N_EXP + 1) * 4);
    int*   fill = (int*)alloc(N_EXP * 4);
    int*   tki  = (int*)alloc((size_t)T_TOK * K_TOP * 4);
    float* tkw  = (float*)alloc((size_t)T_TOK * K_TOP * 4);
    int*   atok = (int*)alloc((size_t)N_ASG * 4);
    float* aw   = (float*)alloc((size_t)N_ASG * 4);
    int*   rowOf= (int*)alloc((size_t)T_TOK * K_TOP * 4);
    float* raw  = (float*)alloc((size_t)T_TOK * N_EXP * 4);
    u16*   xnb  = (u16*)alloc((size_t)T_TOK * D_DIM * 2);
    float* acc  = (float*)alloc((size_t)T_TOK * D_DIM * 4);
    // fast-path: fragment-packed bf16 weights + global h (in-place hg)
    u16* W1f = (u16*)alloc((size_t)(N_EXP + 2) * H_DIM * D_DIM * 2);
    u16* W2f = (u16*)alloc((size_t)(N_EXP + 2) * H_DIM * D_DIM * 2);
    u16* Wgf = (u16*)alloc((size_t)2 * H_DIM * H_DIM * 2);
    u16* h   = (u16*)alloc((size_t)R_TOT * H_DIM * 2);
    alloc(1 << 16);                       // slack: prefetch overruns beyond h land here
    char* markA = wp;                     // end of atomic-tier footprint
    float* outAll = (float*)alloc((size_t)R_TOT * D_DIM * 4);
    char* markB = wp;                     // end of non-atomic-tier footprint
    bool fastA = (size_t)(markA - (char*)d_ws) <= ws_size;
    bool fast2 = (size_t)(markB - (char*)d_ws) <= ws_size;

    hipMemsetAsync(cnt, 0, N_EXP * 4, stream);

    dim3 b256(256);
    rn4_k<<<T_TOK / 4, b256, 0, stream>>>(x, nw, Wr, raw, xnb);
    topk_k<<<T_TOK, dim3(64), 0, stream>>>(raw, ebias, cnt, tki, tkw);
    scan_k<<<1, dim3(64), 0, stream>>>(cnt, offs, fill);
    fill_k<<<T_TOK, dim3(64), 0, stream>>>(tki, tkw, fill, atok, aw, rowOf);

    if (fast2) {
        convAll_k<<<dim3(2 * 66 * 128 + 2 * 64), b256, 0, stream>>>(
            rW1, sW1, rW2, sW2, rWg, sWg, W1f, W2f, Wgf);
        p1_k<<<dim3(GRID_E, 2), b256, 0, stream>>>(xnb, W1f, rb1, sb1, offs, atok, h);
        p2_k<<<dim3(R_TOT / 16), b256, 0, stream>>>(h, Wgf);
        p3_k<0><<<dim3(GRID_E, 4), b256, 0, stream>>>(
            h, W2f, rb2, sb2, offs, atok, aw, nullptr, outAll);
        gather_k<<<T_TOK, b256, 0, stream>>>(x, outAll, rowOf, out);
    } else if (fastA) {
        hipMemsetAsync(acc, 0, (size_t)T_TOK * D_DIM * 4, stream);
        convAll_k<<<dim3(2 * 66 * 128 + 2 * 64), b256, 0, stream>>>(
            rW1, sW1, rW2, sW2, rWg, sWg, W1f, W2f, Wgf);
        p1_k<<<dim3(GRID_E, 2), b256, 0, stream>>>(xnb, W1f, rb1, sb1, offs, atok, h);
        p2_k<<<dim3(R_TOT / 16), b256, 0, stream>>>(h, Wgf);
        p3_k<1><<<dim3(GRID_E, 4), b256, 0, stream>>>(
            h, W2f, rb2, sb2, offs, atok, aw, acc, nullptr);
        final_k<<<(T_TOK * D_DIM) / 1024, b256, 0, stream>>>(x, acc, out);
    } else {
        hipMemsetAsync(acc, 0, (size_t)T_TOK * D_DIM * 4, stream);
        moe_ffn_k<1><<<dim3(1, 64, N_EXP), b256, 0, stream>>>(
            xnb, rW1, rWg, rW2, rb1, rb2, offs, atok, aw, acc);
        moe_ffn_k<0><<<dim3(1, 64, 2), b256, 0, stream>>>(
            xnb, sW1, sWg, sW2, sb1, sb2, offs, atok, aw, acc);
        final_k<<<(T_TOK * D_DIM) / 1024, b256, 0, stream>>>(x, acc, out);
    }
}

// Round 8
// 631.266 us; speedup vs baseline: 1.3537x; 1.0117x over previous
//
#include <hip/hip_runtime.h>
#include <cstdint>
#include <cstddef>

typedef unsigned short u16;
typedef unsigned int u32;
typedef __attribute__((ext_vector_type(8))) short bh8;
typedef __attribute__((ext_vector_type(4))) float fx4;

#define T_TOK 2048
#define D_DIM 1024
#define H_DIM 512
#define N_EXP 64
#define K_TOP 6
#define N_ASG (T_TOK * K_TOP)       // 12288
#define R_TOT (N_ASG + 2 * T_TOK)   // 16384 rows in h-space
#define GRID_E (8 * 9 * 64)         // 4608
#define NCONV (66 * 64 + 66 * 64 + 64)   // 8512 conv jobs (2 k-tiles each)

__device__ __forceinline__ float bf2f(u16 v) {
    union { u32 u; float f; } c; c.u = ((u32)v) << 16; return c.f;
}
__device__ __forceinline__ u16 f2bf(float f) {
    union { u32 u; float f; } c; c.f = f;
    u32 u = c.u;
    return (u16)((u + 0x7fffu + ((u >> 16) & 1u)) >> 16);
}

// ============ prep_k: weight convert (frag-pack, 2 k-tiles/block pipelined)
//              + fused RMSNorm/router in tail blocks (runs concurrently) ============
// conv jobs [0, nconv): W1 66*64, W2 66*64, Wg 64. rn blocks [nconv, nconv+512).
__global__ __launch_bounds__(256) void prep_k(
    const float* __restrict__ x, const float* __restrict__ nw,
    const float* __restrict__ Wr, float* __restrict__ raw, u16* __restrict__ xnb,
    const float* __restrict__ rW1, const float* __restrict__ sW1,
    const float* __restrict__ rW2, const float* __restrict__ sW2,
    const float* __restrict__ rWg, const float* __restrict__ sWg,
    u16* __restrict__ W1f, u16* __restrict__ W2f, u16* __restrict__ Wgf,
    int nconv)
{
    __shared__ __align__(16) char smraw[20608];
    int id = blockIdx.x;
    int tid = threadIdx.x;

    if (id < nconv) {
        const size_t MS = (size_t)H_DIM * D_DIM;
        const float* src; u16* dst;
        int K, N, n0, k0;
        if (id < 4224) {
            int mat = id >> 6, j = id & 63;
            K = D_DIM; N = H_DIM;
            src = (mat < N_EXP ? rW1 + (size_t)mat * MS : sW1 + (size_t)(mat - N_EXP) * MS);
            dst = W1f + (size_t)mat * MS;
            n0 = (j & 7) << 6; k0 = (j >> 3) << 7;
        } else if (id < 8448) {
            int t = id - 4224, mat = t >> 6, j = t & 63;
            K = H_DIM; N = D_DIM;
            src = (mat < N_EXP ? rW2 + (size_t)mat * MS : sW2 + (size_t)(mat - N_EXP) * MS);
            dst = W2f + (size_t)mat * MS;
            n0 = (j & 15) << 6; k0 = (j >> 4) << 7;
        } else {
            int t = id - 8448, mat = t >> 5, j = t & 31;
            K = H_DIM; N = H_DIM;
            src = (mat == 0 ? rWg : sWg);
            dst = Wgf + (size_t)mat * (H_DIM * H_DIM);
            n0 = (j & 7) << 6; k0 = (j >> 3) << 7;
        }
        u16 (*t0)[68] = reinterpret_cast<u16(*)[68]>(smraw);
        u16 (*t1)[68] = reinterpret_cast<u16(*)[68]>(smraw + 8704);
        int kr = tid >> 4, c4 = (tid & 15) << 2;
        int lane = tid & 63, g = tid >> 6, nr = lane & 15, kq = lane >> 4;

        // tile0 load + LDS transpose
        float4 v[4];
        #pragma unroll
        for (int rr = 0; rr < 4; ++rr)
            v[rr] = *(const float4*)(src + (size_t)(k0 + (rr << 4) + kr) * N + n0 + c4);
        #pragma unroll
        for (int rr = 0; rr < 4; ++rr) {
            int k = (rr << 4) + kr;
            t0[c4 + 0][k] = f2bf(v[rr].x);
            t0[c4 + 1][k] = f2bf(v[rr].y);
            t0[c4 + 2][k] = f2bf(v[rr].z);
            t0[c4 + 3][k] = f2bf(v[rr].w);
        }
        __syncthreads();
        // issue tile1 loads (overlap with tile0 frag stores below)
        float4 w4_[4];
        #pragma unroll
        for (int rr = 0; rr < 4; ++rr)
            w4_[rr] = *(const float4*)(src + (size_t)(k0 + 64 + (rr << 4) + kr) * N + n0 + c4);
        // tile0 fragment stores
        #pragma unroll
        for (int f = 0; f < 2; ++f) {
            int fragId = g + (f << 2);
            int ntile = fragId >> 1, kb2 = fragId & 1;
            bh8 vv = *(const bh8*)&t0[(ntile << 4) + nr][(kb2 << 5) + (kq << 3)];
            size_t fi = (((size_t)((n0 >> 4) + ntile) * (size_t)(K >> 5)
                          + (size_t)((k0 >> 5) + kb2)) << 9) + (size_t)(lane << 3);
            *(bh8*)(dst + fi) = vv;
        }
        // tile1 LDS transpose (waits on w4_ loads)
        #pragma unroll
        for (int rr = 0; rr < 4; ++rr) {
            int k = (rr << 4) + kr;
            t1[c4 + 0][k] = f2bf(w4_[rr].x);
            t1[c4 + 1][k] = f2bf(w4_[rr].y);
            t1[c4 + 2][k] = f2bf(w4_[rr].z);
            t1[c4 + 3][k] = f2bf(w4_[rr].w);
        }
        __syncthreads();
        #pragma unroll
        for (int f = 0; f < 2; ++f) {
            int fragId = g + (f << 2);
            int ntile = fragId >> 1, kb2 = fragId & 1;
            bh8 vv = *(const bh8*)&t1[(ntile << 4) + nr][(kb2 << 5) + (kq << 3)];
            size_t fi = (((size_t)((n0 >> 4) + ntile) * (size_t)(K >> 5)
                          + (size_t)((k0 >> 5) + 2 + kb2)) << 9) + (size_t)(lane << 3);
            *(bh8*)(dst + fi) = vv;
        }
        return;
    }

    // ---- rn4 tail blocks: fused RMSNorm + router for 4 tokens ----
    int t0tok = (id - nconv) << 2;
    float* xs = (float*)smraw;                 // [4][1024]
    float* ps = xs + 4 * D_DIM;                // [4][256]
    float* red4 = ps + 4 * 256;                // [4][4]
    int d0 = tid << 2;
    float4 wv = *(const float4*)(nw + d0);
    float4 xv[4];
    #pragma unroll
    for (int tt = 0; tt < 4; ++tt) {
        xv[tt] = *(const float4*)(x + (size_t)(t0tok + tt) * D_DIM + d0);
        float ss = xv[tt].x * xv[tt].x + xv[tt].y * xv[tt].y
                 + xv[tt].z * xv[tt].z + xv[tt].w * xv[tt].w;
        #pragma unroll
        for (int o = 32; o > 0; o >>= 1) ss += __shfl_down(ss, o);
        if ((tid & 63) == 0) red4[tt * 4 + (tid >> 6)] = ss;
    }
    __syncthreads();
    #pragma unroll
    for (int tt = 0; tt < 4; ++tt) {
        float ms = (red4[tt * 4 + 0] + red4[tt * 4 + 1] + red4[tt * 4 + 2] + red4[tt * 4 + 3])
                 * (1.f / (float)D_DIM);
        float sc = rsqrtf(ms + 1.1920929e-07f);
        float4 xf;
        xf.x = xv[tt].x * sc * wv.x;
        xf.y = xv[tt].y * sc * wv.y;
        xf.z = xv[tt].z * sc * wv.z;
        xf.w = xv[tt].w * sc * wv.w;
        *(float4*)&xs[tt * D_DIM + d0] = xf;
        ushort4 ob;
        ob.x = f2bf(xf.x); ob.y = f2bf(xf.y); ob.z = f2bf(xf.z); ob.w = f2bf(xf.w);
        *(ushort4*)(xnb + (size_t)(t0tok + tt) * D_DIM + d0) = ob;
    }
    __syncthreads();
    int e = tid & 63, part = tid >> 6;
    const float* wr = Wr + (size_t)e * D_DIM + part * 256;
    float s0 = 0.f, s1 = 0.f, s2 = 0.f, s3 = 0.f;
    const float* xp0 = &xs[0 * D_DIM + part * 256];
    const float* xp1 = &xs[1 * D_DIM + part * 256];
    const float* xp2 = &xs[2 * D_DIM + part * 256];
    const float* xp3 = &xs[3 * D_DIM + part * 256];
    #pragma unroll 4
    for (int i = 0; i < 256; i += 4) {
        float4 w4 = *(const float4*)(wr + i);
        s0 += xp0[i] * w4.x + xp0[i+1] * w4.y + xp0[i+2] * w4.z + xp0[i+3] * w4.w;
        s1 += xp1[i] * w4.x + xp1[i+1] * w4.y + xp1[i+2] * w4.z + xp1[i+3] * w4.w;
        s2 += xp2[i] * w4.x + xp2[i+1] * w4.y + xp2[i+2] * w4.z + xp2[i+3] * w4.w;
        s3 += xp3[i] * w4.x + xp3[i+1] * w4.y + xp3[i+2] * w4.z + xp3[i+3] * w4.w;
    }
    ps[0 * 256 + tid] = s0; ps[1 * 256 + tid] = s1;
    ps[2 * 256 + tid] = s2; ps[3 * 256 + tid] = s3;
    __syncthreads();
    if (part == 0) {
        #pragma unroll
        for (int tt = 0; tt < 4; ++tt)
            raw[(size_t)(t0tok + tt) * N_EXP + e] =
                ps[tt * 256 + e] + ps[tt * 256 + 64 + e]
              + ps[tt * 256 + 128 + e] + ps[tt * 256 + 192 + e];
    }
}

// ---------------- top-k (one wave per token), fp32 ----------------
__global__ void topk_k(const float* __restrict__ raw, const float* __restrict__ ebias,
                       int* __restrict__ cnt, int* __restrict__ tki, float* __restrict__ tkw)
{
    int t = blockIdx.x, lane = threadIdx.x;
    float r = raw[(size_t)t * N_EXP + lane];
    float cur = r + ebias[lane];
    int selI[K_TOP]; float selR[K_TOP];
    #pragma unroll
    for (int k = 0; k < K_TOP; ++k) {
        float v = cur; int id = lane;
        #pragma unroll
        for (int o = 32; o > 0; o >>= 1) {
            float v2 = __shfl_down(v, o); int i2 = __shfl_down(id, o);
            if (v2 > v || (v2 == v && i2 < id)) { v = v2; id = i2; }
        }
        id = __shfl(id, 0);
        if (lane == id) cur = -3.4e38f;
        selI[k] = id;
        selR[k] = __shfl(r, id);
    }
    float s = 0.f;
    #pragma unroll
    for (int k = 0; k < K_TOP; ++k) s += selR[k];
    if (lane < K_TOP) {
        tki[t * K_TOP + lane] = selI[lane];
        tkw[t * K_TOP + lane] = selR[lane] / s;
        atomicAdd(&cnt[selI[lane]], 1);
    }
}

// parallel 64-lane exclusive scan
__global__ void scan_k(const int* __restrict__ cnt, int* __restrict__ offs, int* __restrict__ fill)
{
    int lane = threadIdx.x;          // 64
    int c = cnt[lane];
    int s = c;
    #pragma unroll
    for (int o = 1; o < 64; o <<= 1) {
        int v = __shfl_up(s, o);
        if (lane >= o) s += v;
    }
    int excl = s - c;
    offs[lane] = excl;
    fill[lane] = excl;
    if (lane == 63) offs[N_EXP] = s;
}

__global__ void fill_k(const int* __restrict__ tki, const float* __restrict__ tkw,
                       int* __restrict__ fill, int* __restrict__ atok, float* __restrict__ aw,
                       int* __restrict__ rowOf)
{
    int t = blockIdx.x, lane = threadIdx.x;
    if (lane < K_TOP) {
        int e = tki[t * K_TOP + lane];
        int p = atomicAdd(&fill[e], 1);
        atok[p] = t;
        aw[p] = tkw[t * K_TOP + lane];
        rowOf[t * K_TOP + lane] = p;
    }
}

// ===== shared decode for expert-aligned row slabs (p1/p3) =====
__device__ __forceinline__ bool slabDecode(
    int bx, const int* __restrict__ offs,
    int& e, int& rowBase, int& rows, int& tokBase)
{
    int xcd = bx & 7, rest = bx >> 3, grp = rest >> 6, slab = rest & 63;
    if (grp < 8) {
        e = (grp << 3) + xcd;
        int s0 = offs[e], s1 = offs[e + 1];
        rowBase = s0 + (slab << 5);
        if (rowBase >= s1) return false;
        rows = s1 - rowBase; if (rows > 32) rows = 32;
        tokBase = -1;
        return true;
    }
    int f = (slab << 3) + xcd;
    if (f >= 128) return false;
    int sh = f & 1;
    e = N_EXP + sh;
    tokBase = (f >> 1) << 5;
    rowBase = N_ASG + (sh << 11) + tokBase;
    rows = 32;
    return true;
}

// ===== phase 1: h[r][512] = xnb[tok(r)] @ W1[e] + b1[e]  (K=1024) =====
// epilogue via LDS bounce -> coalesced uint4 stores
__global__ __launch_bounds__(256, 4) void p1_k(
    const u16* __restrict__ xnb, const u16* __restrict__ W1f,
    const float* __restrict__ rb1, const float* __restrict__ sb1,
    const int* __restrict__ offs, const int* __restrict__ atok,
    u16* __restrict__ h)
{
    int e, rowBase, rows, tokBase;
    if (!slabDecode(blockIdx.x, offs, e, rowBase, rows, tokBase)) return;

    __shared__ int tok[32];
    __shared__ u16 hs[32][264];
    int tid = threadIdx.x;
    if (tid < 32) {
        int cl = tid < rows ? tid : rows - 1;
        tok[tid] = (tokBase < 0) ? atok[rowBase + cl] : tokBase + tid;
    }
    __syncthreads();

    int w = tid >> 6, lane = tid & 63, quad = lane >> 4, l15 = lane & 15;
    int cg = blockIdx.y;
    int nt0 = (cg << 4) + (w << 2);                 // ntile in [0,32)
    const u16* bp = W1f + (size_t)e * (H_DIM * D_DIM)
                  + (((size_t)nt0 << 5) << 9) + (lane << 3);
    const u16* a0p = xnb + (size_t)tok[l15] * D_DIM + (quad << 3);
    const u16* a1p = xnb + (size_t)tok[16 + l15] * D_DIM + (quad << 3);
    const float* b1 = (tokBase < 0) ? rb1 + e * H_DIM : sb1 + (e - N_EXP) * H_DIM;

    fx4 ac0[4] = {}, ac1[4] = {};
    bh8 bA[4], bB[4], aA0, aA1, aB0, aB1;
    #pragma unroll
    for (int ct = 0; ct < 4; ++ct) bA[ct] = *(const bh8*)(bp + ((size_t)(ct << 5) << 9));
    aA0 = *(const bh8*)a0p; aA1 = *(const bh8*)a1p;
    #pragma unroll 1
    for (int kb = 0; kb < 32; kb += 2) {
        #pragma unroll
        for (int ct = 0; ct < 4; ++ct) bB[ct] = *(const bh8*)(bp + (((ct << 5) + kb + 1) << 9));
        aB0 = *(const bh8*)(a0p + ((kb + 1) << 5));
        aB1 = *(const bh8*)(a1p + ((kb + 1) << 5));
        #pragma unroll
        for (int ct = 0; ct < 4; ++ct) {
            ac0[ct] = __builtin_amdgcn_mfma_f32_16x16x32_bf16(aA0, bA[ct], ac0[ct], 0, 0, 0);
            ac1[ct] = __builtin_amdgcn_mfma_f32_16x16x32_bf16(aA1, bA[ct], ac1[ct], 0, 0, 0);
        }
        #pragma unroll
        for (int ct = 0; ct < 4; ++ct) bA[ct] = *(const bh8*)(bp + (((ct << 5) + kb + 2) << 9));
        aA0 = *(const bh8*)(a0p + ((kb + 2) << 5));     // last iter overrun: valid ws memory
        aA1 = *(const bh8*)(a1p + ((kb + 2) << 5));
        #pragma unroll
        for (int ct = 0; ct < 4; ++ct) {
            ac0[ct] = __builtin_amdgcn_mfma_f32_16x16x32_bf16(aB0, bB[ct], ac0[ct], 0, 0, 0);
            ac1[ct] = __builtin_amdgcn_mfma_f32_16x16x32_bf16(aB1, bB[ct], ac1[ct], 0, 0, 0);
        }
    }
    #pragma unroll
    for (int ct = 0; ct < 4; ++ct) {
        int lcol = (((w << 2) + ct) << 4) + l15;          // 0..255
        float bv = b1[(cg << 8) + lcol];
        #pragma unroll
        for (int r = 0; r < 4; ++r) {
            int r0 = (quad << 2) + r;
            hs[r0][lcol]      = f2bf(ac0[ct][r] + bv);
            hs[16 + r0][lcol] = f2bf(ac1[ct][r] + bv);
        }
    }
    __syncthreads();
    #pragma unroll
    for (int p = 0; p < 4; ++p) {
        int idx = tid + (p << 8);                 // 0..1023
        int r = idx >> 5, cs = (idx & 31) << 3;
        if (r < rows)
            *(uint4*)&h[(size_t)(rowBase + r) * H_DIM + (cg << 8) + cs] = *(uint4*)&hs[r][cs];
    }
}

// ===== phase 2: h[r] <- h[r] * silu(h[r] @ Wg), IN PLACE  (K=512) =====
__global__ __launch_bounds__(256, 4) void p2_k(
    u16* __restrict__ h, const u16* __restrict__ Wgf)
{
    int rowBase = blockIdx.x << 4;
    int tid = threadIdx.x;
    int w = tid >> 6, lane = tid & 63, quad = lane >> 4, l15 = lane & 15;
    const u16* bp = Wgf + (rowBase < N_ASG ? 0 : (size_t)(H_DIM * H_DIM)) + (lane << 3);
    const u16* a0p = h + (size_t)(rowBase + l15) * H_DIM + (quad << 3);

    fx4 ac[8] = {};
    bh8 bA[8], bB[8], aA, aB;
    #pragma unroll
    for (int ct = 0; ct < 8; ++ct)
        bA[ct] = *(const bh8*)(bp + ((((size_t)(w << 3) + ct) << 4) << 9));
    aA = *(const bh8*)a0p;
    #pragma unroll 1
    for (int kb = 0; kb < 16; kb += 2) {
        #pragma unroll
        for (int ct = 0; ct < 8; ++ct)
            bB[ct] = *(const bh8*)(bp + (((((size_t)(w << 3) + ct) << 4) + kb + 1) << 9));
        aB = *(const bh8*)(a0p + ((kb + 1) << 5));
        #pragma unroll
        for (int ct = 0; ct < 8; ++ct)
            ac[ct] = __builtin_amdgcn_mfma_f32_16x16x32_bf16(aA, bA[ct], ac[ct], 0, 0, 0);
        #pragma unroll
        for (int ct = 0; ct < 8; ++ct)
            bA[ct] = *(const bh8*)(bp + (((((size_t)(w << 3) + ct) << 4) + kb + 2) << 9));
        aA = *(const bh8*)(a0p + ((kb + 2) << 5));
        #pragma unroll
        for (int ct = 0; ct < 8; ++ct)
            ac[ct] = __builtin_amdgcn_mfma_f32_16x16x32_bf16(aB, bB[ct], ac[ct], 0, 0, 0);
    }
    __syncthreads();   // all reads of this block's rows complete before in-place write
    #pragma unroll
    for (int ct = 0; ct < 8; ++ct) {
        int col = (((w << 3) + ct) << 4) + l15;
        #pragma unroll
        for (int r = 0; r < 4; ++r) {
            int row = rowBase + (quad << 2) + r;
            size_t i = (size_t)row * H_DIM + col;
            float g = ac[ct][r], hv = bf2f(h[i]);
            h[i] = f2bf(hv * g * (1.f / (1.f + __expf(-g))));
        }
    }
}

// ===== phase 3: out rows = wt(r)*(hg[r] @ W2[e] + b2[e])  (K=512, N=1024) =====
// ATOM=1: atomicAdd into acc. ATOM=0: LDS-bounced coalesced float4 stores to outAll.
template<int ATOM>
__global__ __launch_bounds__(256, 4) void p3_k(
    const u16* __restrict__ hg, const u16* __restrict__ W2f,
    const float* __restrict__ rb2, const float* __restrict__ sb2,
    const int* __restrict__ offs, const int* __restrict__ atok,
    const float* __restrict__ aw, float* __restrict__ accG, float* __restrict__ outAll)
{
    int e, rowBase, rows, tokBase;
    if (!slabDecode(blockIdx.x, offs, e, rowBase, rows, tokBase)) return;

    __shared__ int tok[32];
    __shared__ float wt[32];
    __shared__ float os[ATOM ? 1 : 32 * 260];
    int tid = threadIdx.x;
    if (tid < 32) {
        int cl = tid < rows ? tid : rows - 1;
        if (tokBase < 0) { tok[tid] = atok[rowBase + cl]; wt[tid] = aw[rowBase + cl]; }
        else             { tok[tid] = tokBase + tid;      wt[tid] = 1.0f; }
    }
    __syncthreads();

    int w = tid >> 6, lane = tid & 63, quad = lane >> 4, l15 = lane & 15;
    int cg = blockIdx.y;
    int nt0 = (cg << 4) + (w << 2);                 // ntile in [0,64)
    const u16* bp = W2f + (size_t)e * (H_DIM * D_DIM)
                  + (((size_t)nt0 << 4) << 9) + (lane << 3);
    const u16* a0p = hg + (size_t)(rowBase + l15) * H_DIM + (quad << 3);
    const u16* a1p = hg + (size_t)(rowBase + 16 + l15) * H_DIM + (quad << 3);
    const float* b2 = (tokBase < 0) ? rb2 + e * D_DIM : sb2 + (e - N_EXP) * D_DIM;

    fx4 ac0[4] = {}, ac1[4] = {};
    bh8 bA[4], bB[4], aA0, aA1, aB0, aB1;
    #pragma unroll
    for (int ct = 0; ct < 4; ++ct) bA[ct] = *(const bh8*)(bp + ((size_t)(ct << 4) << 9));
    aA0 = *(const bh8*)a0p; aA1 = *(const bh8*)a1p;
    #pragma unroll 1
    for (int kb = 0; kb < 16; kb += 2) {
        #pragma unroll
        for (int ct = 0; ct < 4; ++ct) bB[ct] = *(const bh8*)(bp + (((ct << 4) + kb + 1) << 9));
        aB0 = *(const bh8*)(a0p + ((kb + 1) << 5));
        aB1 = *(const bh8*)(a1p + ((kb + 1) << 5));
        #pragma unroll
        for (int ct = 0; ct < 4; ++ct) {
            ac0[ct] = __builtin_amdgcn_mfma_f32_16x16x32_bf16(aA0, bA[ct], ac0[ct], 0, 0, 0);
            ac1[ct] = __builtin_amdgcn_mfma_f32_16x16x32_bf16(aA1, bA[ct], ac1[ct], 0, 0, 0);
        }
        #pragma unroll
        for (int ct = 0; ct < 4; ++ct) bA[ct] = *(const bh8*)(bp + (((ct << 4) + kb + 2) << 9));
        aA0 = *(const bh8*)(a0p + ((kb + 2) << 5));
        aA1 = *(const bh8*)(a1p + ((kb + 2) << 5));
        #pragma unroll
        for (int ct = 0; ct < 4; ++ct) {
            ac0[ct] = __builtin_amdgcn_mfma_f32_16x16x32_bf16(aB0, bB[ct], ac0[ct], 0, 0, 0);
            ac1[ct] = __builtin_amdgcn_mfma_f32_16x16x32_bf16(aB1, bB[ct], ac1[ct], 0, 0, 0);
        }
    }
    if (ATOM) {
        #pragma unroll
        for (int ct = 0; ct < 4; ++ct) {
            int col = ((nt0 + ct) << 4) + l15;
            float bv = b2[col];
            #pragma unroll
            for (int r = 0; r < 4; ++r) {
                int r0 = (quad << 2) + r;
                if (r0 < rows)
                    atomicAdd(&accG[(size_t)tok[r0] * D_DIM + col], wt[r0] * (ac0[ct][r] + bv));
                int r1 = 16 + r0;
                if (r1 < rows)
                    atomicAdd(&accG[(size_t)tok[r1] * D_DIM + col], wt[r1] * (ac1[ct][r] + bv));
            }
        }
    } else {
        #pragma unroll
        for (int ct = 0; ct < 4; ++ct) {
            int lcol = (((w << 2) + ct) << 4) + l15;       // 0..255
            float bv = b2[(cg << 8) + lcol];
            #pragma unroll
            for (int r = 0; r < 4; ++r) {
                int r0 = (quad << 2) + r;
                os[r0 * 260 + lcol]        = wt[r0] * (ac0[ct][r] + bv);
                os[(16 + r0) * 260 + lcol] = wt[16 + r0] * (ac1[ct][r] + bv);
            }
        }
        __syncthreads();
        #pragma unroll
        for (int p = 0; p < 8; ++p) {
            int idx = tid + (p << 8);             // 0..2047
            int r = idx >> 6, cs = (idx & 63) << 2;
            if (r < rows)
                *(float4*)&outAll[(size_t)(rowBase + r) * D_DIM + (cg << 8) + cs]
                    = *(float4*)&os[r * 260 + cs];
        }
    }
}

// ---------------- gather: out[t] = x[t] + sum of 6 routed rows + 2 shared rows ----------------
__global__ __launch_bounds__(256) void gather_k(
    const float* __restrict__ x, const float* __restrict__ outAll,
    const int* __restrict__ rowOf, float* __restrict__ out)
{
    int t = blockIdx.x, tid = threadIdx.x;
    __shared__ int rws[K_TOP];
    if (tid < K_TOP) rws[tid] = rowOf[t * K_TOP + tid];
    __syncthreads();
    int d0 = tid << 2;
    size_t base = (size_t)t * D_DIM + d0;
    float4 xv = *(const float4*)(x + base);
    float4 s = *(const float4*)(outAll + (size_t)(N_ASG + t) * D_DIM + d0);
    float4 s1 = *(const float4*)(outAll + (size_t)(N_ASG + T_TOK + t) * D_DIM + d0);
    s.x += s1.x; s.y += s1.y; s.z += s1.z; s.w += s1.w;
    #pragma unroll
    for (int k = 0; k < K_TOP; ++k) {
        float4 v = *(const float4*)(outAll + (size_t)rws[k] * D_DIM + d0);
        s.x += v.x; s.y += v.y; s.z += v.z; s.w += v.w;
    }
    float4 o;
    o.x = xv.x + s.x; o.y = xv.y + s.y; o.z = xv.z + s.z; o.w = xv.w + s.w;
    *(float4*)(out + base) = o;
}

// ============ fallback fused FFN (raw fp32 weights), used only if workspace too small ============
template<int ROUTED>
__global__ __launch_bounds__(256) void moe_ffn_k(
    const u16* __restrict__ xnb,
    const float* __restrict__ W1b, const float* __restrict__ Wg,
    const float* __restrict__ W2b,
    const float* __restrict__ b1b, const float* __restrict__ b2b,
    const int* __restrict__ offs, const int* __restrict__ atok,
    const float* __restrict__ aw, float* __restrict__ accG)
{
    int e = blockIdx.z;
    int start = ROUTED ? offs[e] : 0;
    int end   = ROUTED ? offs[e + 1] : T_TOK;
    int rowBase = start + (blockIdx.y << 5);
    if (rowBase >= end) return;
    int rows = end - rowBase; if (rows > 32) rows = 32;

    __shared__ int   tok[32];
    __shared__ float wt[32];
    __shared__ u16 hA[32 * 520];
    __shared__ u16 hG[32 * 520];
    __shared__ u16 As[32 * 32];
    __shared__ u16 Bs[64 * 36];

    int tid = threadIdx.x;
    if (tid < 32) {
        int cl = rowBase + tid; if (cl >= end) cl = end - 1;
        tok[tid] = ROUTED ? atok[cl] : cl;
        wt[tid]  = ROUTED ? aw[cl] : 1.0f;
    }
    __syncthreads();

    const float* W1 = W1b + (size_t)e * (D_DIM * H_DIM);
    const float* W2 = W2b + (size_t)e * (D_DIM * H_DIM);
    const float* b1 = b1b + e * H_DIM;
    const float* b2 = b2b + e * D_DIM;

    int w = tid >> 6, lane = tid & 63, quad = lane >> 4, l15 = lane & 15;
    int sr2 = tid >> 3, sc2 = (tid & 7) << 2;

    for (int nc = 0; nc < 8; ++nc) {
        int n0 = nc << 6;
        fx4 a0 = {}; fx4 a1 = {};
        for (int kc = 0; kc < 32; ++kc) {
            int kb = kc << 5;
            int2 av = *(const int2*)(xnb + (size_t)tok[sr2] * D_DIM + kb + sc2);
            const float* cp = W1 + n0 + lane;
            int kx = kb + (w << 3);
            u32 p[4];
            #pragma unroll
            for (int jj = 0; jj < 4; ++jj) {
                u32 lo = f2bf(cp[(size_t)(kx + 2 * jj) * H_DIM]);
                u32 hi = f2bf(cp[(size_t)(kx + 2 * jj + 1) * H_DIM]);
                p[jj] = lo | (hi << 16);
            }
            __syncthreads();
            *(int2*)&As[sr2 * 32 + sc2] = av;
            u16* bsw = &Bs[lane * 36 + (w << 3)];
            uint2 q0; q0.x = p[0]; q0.y = p[1];
            uint2 q1; q1.x = p[2]; q1.y = p[3];
            *(uint2*)bsw = q0;
            *(uint2*)(bsw + 4) = q1;
            __syncthreads();
            bh8 af0 = *(const bh8*)&As[l15 * 32 + (quad << 3)];
            bh8 af1 = *(const bh8*)&As[(16 + l15) * 32 + (quad << 3)];
            const u16* brp = &Bs[((w << 4) + l15) * 36 + (quad << 3)];
            union { bh8 v; uint2 u2[2]; } bf;
            bf.u2[0] = *(const uint2*)brp;
            bf.u2[1] = *(const uint2*)(brp + 4);
            a0 = __builtin_amdgcn_mfma_f32_16x16x32_bf16(af0, bf.v, a0, 0, 0, 0);
            a1 = __builtin_amdgcn_mfma_f32_16x16x32_bf16(af1, bf.v, a1, 0, 0, 0);
        }
        int col = n0 + (w << 4) + l15;
        float bv = b1[col];
        #pragma unroll
        for (int r = 0; r < 4; ++r) {
            hA[((quad << 2) + r) * 520 + col]      = f2bf(a0[r] + bv);
            hA[(16 + (quad << 2) + r) * 520 + col] = f2bf(a1[r] + bv);
        }
    }
    __syncthreads();

    for (int nc = 0; nc < 8; ++nc) {
        int n0 = nc << 6;
        fx4 a0 = {}; fx4 a1 = {};
        for (int kc = 0; kc < 16; ++kc) {
            int kb = kc << 5;
            const float* cp = Wg + n0 + lane;
            int kx = kb + (w << 3);
            u32 p[4];
            #pragma unroll
            for (int jj = 0; jj < 4; ++jj) {
                u32 lo = f2bf(cp[(size_t)(kx + 2 * jj) * H_DIM]);
                u32 hi = f2bf(cp[(size_t)(kx + 2 * jj + 1) * H_DIM]);
                p[jj] = lo | (hi << 16);
            }
            __syncthreads();
            u16* bsw = &Bs[lane * 36 + (w << 3)];
            uint2 q0; q0.x = p[0]; q0.y = p[1];
            uint2 q1; q1.x = p[2]; q1.y = p[3];
            *(uint2*)bsw = q0;
            *(uint2*)(bsw + 4) = q1;
            __syncthreads();
            bh8 af0 = *(const bh8*)&hA[l15 * 520 + kb + (quad << 3)];
            bh8 af1 = *(const bh8*)&hA[(16 + l15) * 520 + kb + (quad << 3)];
            const u16* brp = &Bs[((w << 4) + l15) * 36 + (quad << 3)];
            union { bh8 v; uint2 u2[2]; } bf;
            bf.u2[0] = *(const uint2*)brp;
            bf.u2[1] = *(const uint2*)(brp + 4);
            a0 = __builtin_amdgcn_mfma_f32_16x16x32_bf16(af0, bf.v, a0, 0, 0, 0);
            a1 = __builtin_amdgcn_mfma_f32_16x16x32_bf16(af1, bf.v, a1, 0, 0, 0);
        }
        int col = n0 + (w << 4) + l15;
        #pragma unroll
        for (int r = 0; r < 4; ++r) {
            int r0 = (quad << 2) + r;
            float h0 = bf2f(hA[r0 * 520 + col]);
            float g0 = a0[r];
            hG[r0 * 520 + col] = f2bf(h0 * g0 * (1.f / (1.f + __expf(-g0))));
            int r1 = 16 + r0;
            float h1 = bf2f(hA[r1 * 520 + col]);
            float g1 = a1[r];
            hG[r1 * 520 + col] = f2bf(h1 * g1 * (1.f / (1.f + __expf(-g1))));
        }
    }
    __syncthreads();

    for (int nc = 0; nc < 16; ++nc) {
        int n0 = nc << 6;
        fx4 a0 = {}; fx4 a1 = {};
        for (int kc = 0; kc < 16; ++kc) {
            int kb = kc << 5;
            const float* cp = W2 + n0 + lane;
            int kx = kb + (w << 3);
            u32 p[4];
            #pragma unroll
            for (int jj = 0; jj < 4; ++jj) {
                u32 lo = f2bf(cp[(size_t)(kx + 2 * jj) * D_DIM]);
                u32 hi = f2bf(cp[(size_t)(kx + 2 * jj + 1) * D_DIM]);
                p[jj] = lo | (hi << 16);
            }
            __syncthreads();
            u16* bsw = &Bs[lane * 36 + (w << 3)];
            uint2 q0; q0.x = p[0]; q0.y = p[1];
            uint2 q1; q1.x = p[2]; q1.y = p[3];
            *(uint2*)bsw = q0;
            *(uint2*)(bsw + 4) = q1;
            __syncthreads();
            bh8 af0 = *(const bh8*)&hG[l15 * 520 + kb + (quad << 3)];
            bh8 af1 = *(const bh8*)&hG[(16 + l15) * 520 + kb + (quad << 3)];
            const u16* brp = &Bs[((w << 4) + l15) * 36 + (quad << 3)];
            union { bh8 v; uint2 u2[2]; } bf;
            bf.u2[0] = *(const uint2*)brp;
            bf.u2[1] = *(const uint2*)(brp + 4);
            a0 = __builtin_amdgcn_mfma_f32_16x16x32_bf16(af0, bf.v, a0, 0, 0, 0);
            a1 = __builtin_amdgcn_mfma_f32_16x16x32_bf16(af1, bf.v, a1, 0, 0, 0);
        }
        int col = n0 + (w << 4) + l15;
        float bv = b2[col];
        #pragma unroll
        for (int r = 0; r < 4; ++r) {
            int lr0 = (quad << 2) + r;
            if (lr0 < rows)
                atomicAdd(&accG[(size_t)tok[lr0] * D_DIM + col], wt[lr0] * (a0[r] + bv));
            int lr1 = 16 + lr0;
            if (lr1 < rows)
                atomicAdd(&accG[(size_t)tok[lr1] * D_DIM + col], wt[lr1] * (a1[r] + bv));
        }
    }
}

// ---------------- final (atomic tiers): out = x + acc ----------------
__global__ __launch_bounds__(256) void final_k(
    const float* __restrict__ x, const float* __restrict__ acc, float* __restrict__ out)
{
    size_t i = ((size_t)blockIdx.x * 256 + threadIdx.x) << 2;
    float4 xv = *(const float4*)(x + i);
    float4 a = *(const float4*)(acc + i);
    float4 o;
    o.x = xv.x + a.x;
    o.y = xv.y + a.y;
    o.z = xv.z + a.z;
    o.w = xv.w + a.w;
    *(float4*)(out + i) = o;
}

extern "C" void kernel_launch(void* const* d_in, const int* in_sizes, int n_in,
                              void* d_out, int out_size, void* d_ws, size_t ws_size,
                              hipStream_t stream)
{
    const float* x     = (const float*)d_in[0];
    const float* nw    = (const float*)d_in[1];
    const float* Wr    = (const float*)d_in[2];
    const float* sW1   = (const float*)d_in[3];
    const float* sb1   = (const float*)d_in[4];
    const float* sW2   = (const float*)d_in[5];
    const float* sb2   = (const float*)d_in[6];
    const float* sWg   = (const float*)d_in[7];
    const float* rW1   = (const float*)d_in[8];
    const float* rb1   = (const float*)d_in[9];
    const float* rW2   = (const float*)d_in[10];
    const float* rb2   = (const float*)d_in[11];
    const float* rWg   = (const float*)d_in[12];
    const float* ebias = (const float*)d_in[13];
    float* out = (float*)d_out;
    (void)in_sizes; (void)n_in; (void)out_size;

    char* wp = (char*)d_ws;
    auto alloc = [&](size_t b) { char* p = wp; wp += (b + 255) & ~(size_t)255; return p; };
    int*   cnt  = (int*)alloc(N_EXP * 4);
    int*   offs = (int*)alloc((N_EXP + 1) * 4);
    int*   fill = (int*)alloc(N_EXP * 4);
    int*   tki  = (int*)alloc((size_t)T_TOK * K_TOP * 4);
    float* tkw  = (float*)alloc((size_t)T_TOK * K_TOP * 4);
    int*   atok = (int*)alloc((size_t)N_ASG * 4);
    float* aw   = (float*)alloc((size_t)N_ASG * 4);
    int*   rowOf= (int*)alloc((size_t)T_TOK * K_TOP * 4);
    float* raw  = (float*)alloc((size_t)T_TOK * N_EXP * 4);
    u16*   xnb  = (u16*)alloc((size_t)T_TOK * D_DIM * 2);
    float* acc  = (float*)alloc((size_t)T_TOK * D_DIM * 4);
    // fast-path: fragment-packed bf16 weights + global h (in-place hg)
    u16* W1f = (u16*)alloc((size_t)(N_EXP + 2) * H_DIM * D_DIM * 2);
    u16* W2f = (u16*)alloc((size_t)(N_EXP + 2) * H_DIM * D_DIM * 2);
    u16* Wgf = (u16*)alloc((size_t)2 * H_DIM * H_DIM * 2);
    u16* h   = (u16*)alloc((size_t)R_TOT * H_DIM * 2);
    alloc(1 << 16);                       // slack: prefetch overruns beyond h land here
    char* markA = wp;                     // end of atomic-tier footprint
    float* outAll = (float*)alloc((size_t)R_TOT * D_DIM * 4);
    char* markB = wp;                     // end of non-atomic-tier footprint
    bool fastA = (size_t)(markA - (char*)d_ws) <= ws_size;
    bool fast2 = (size_t)(markB - (char*)d_ws) <= ws_size;

    hipMemsetAsync(cnt, 0, N_EXP * 4, stream);

    dim3 b256(256);
    if (fast2 || fastA) {
        // conv (all weights) + rn4 concurrently in one launch
        prep_k<<<dim3(NCONV + T_TOK / 4), b256, 0, stream>>>(
            x, nw, Wr, raw, xnb, rW1, sW1, rW2, sW2, rWg, sWg, W1f, W2f, Wgf, NCONV);
    } else {
        prep_k<<<dim3(T_TOK / 4), b256, 0, stream>>>(
            x, nw, Wr, raw, xnb, rW1, sW1, rW2, sW2, rWg, sWg,
            nullptr, nullptr, nullptr, 0);
    }
    topk_k<<<T_TOK, dim3(64), 0, stream>>>(raw, ebias, cnt, tki, tkw);
    scan_k<<<1, dim3(64), 0, stream>>>(cnt, offs, fill);
    fill_k<<<T_TOK, dim3(64), 0, stream>>>(tki, tkw, fill, atok, aw, rowOf);

    if (fast2) {
        p1_k<<<dim3(GRID_E, 2), b256, 0, stream>>>(xnb, W1f, rb1, sb1, offs, atok, h);
        p2_k<<<dim3(R_TOT / 16), b256, 0, stream>>>(h, Wgf);
        p3_k<0><<<dim3(GRID_E, 4), b256, 0, stream>>>(
            h, W2f, rb2, sb2, offs, atok, aw, nullptr, outAll);
        gather_k<<<T_TOK, b256, 0, stream>>>(x, outAll, rowOf, out);
    } else if (fastA) {
        hipMemsetAsync(acc, 0, (size_t)T_TOK * D_DIM * 4, stream);
        p1_k<<<dim3(GRID_E, 2), b256, 0, stream>>>(xnb, W1f, rb1, sb1, offs, atok, h);
        p2_k<<<dim3(R_TOT / 16), b256, 0, stream>>>(h, Wgf);
        p3_k<1><<<dim3(GRID_E, 4), b256, 0, stream>>>(
            h, W2f, rb2, sb2, offs, atok, aw, acc, nullptr);
        final_k<<<(T_TOK * D_DIM) / 1024, b256, 0, stream>>>(x, acc, out);
    } else {
        hipMemsetAsync(acc, 0, (size_t)T_TOK * D_DIM * 4, stream);
        moe_ffn_k<1><<<dim3(1, 64, N_EXP), b256, 0, stream>>>(
            xnb, rW1, rWg, rW2, rb1, rb2, offs, atok, aw, acc);
        moe_ffn_k<0><<<dim3(1, 64, 2), b256, 0, stream>>>(
            xnb, sW1, sWg, sW2, sb1, sb2, offs, atok, aw, acc);
        final_k<<<(T_TOK * D_DIM) / 1024, b256, 0, stream>>>(x, acc, out);
    }
}